// Round 3
// baseline (1896.623 us; speedup 1.0000x reference)
//
#include <hip/hip_runtime.h>
#include <math.h>

#define BB 4
#define CH 256
#define CCH 64
#define HH 64
#define WW 64
#define HWN 4096

__device__ __forceinline__ float sigmoidf_(float v){ return 1.0f/(1.0f+__expf(-v)); }

// ---------------- K0: transpose enc_w (64,2304) -> wT (2304,64) ----------------
__global__ __launch_bounds__(256) void k_wt(const float* __restrict__ w, float* __restrict__ wT){
    int i = blockIdx.x*256 + threadIdx.x;
    if (i < 2304*64){ int ck = i>>6, o = i&63; wT[i] = w[o*2304 + ck]; }
}

// ---------------- K1: base = x+y, per-(b,c) sum ----------------
__global__ __launch_bounds__(256) void k_base_sum(const float* __restrict__ x, const float* __restrict__ y,
                                                  float* __restrict__ base, float* __restrict__ sums){
    int bc = blockIdx.x, tid = threadIdx.x;
    const float* xp = x + (size_t)bc*HWN;
    const float* yp = y + (size_t)bc*HWN;
    float* bp = base + (size_t)bc*HWN;
    float s = 0.f;
    for (int i=tid;i<HWN;i+=256){ float v = xp[i]+yp[i]; bp[i]=v; s+=v; }
    __shared__ float red[256];
    red[tid]=s; __syncthreads();
    for (int off=128; off>0; off>>=1){ if (tid<off) red[tid]+=red[tid+off]; __syncthreads(); }
    if (tid==0) sums[bc]=red[0];
}

// ---------------- K2: SE MLP -> scale = 1 + sigmoid(relu(mean@w1T)@w2T) ----------------
__global__ __launch_bounds__(256) void k_se(const float* __restrict__ sums, const float* __restrict__ w1,
                                            const float* __restrict__ w2, float* __restrict__ scale){
    int b = blockIdx.x, tid = threadIdx.x;
    __shared__ float sm[256];
    __shared__ float hid[16];
    sm[tid] = sums[b*256+tid]*(1.0f/4096.0f);
    __syncthreads();
    if (tid<16){
        float a=0.f; const float* wp = w1 + tid*256;
        for (int c=0;c<256;c++) a += sm[c]*wp[c];
        hid[tid]=fmaxf(a,0.f);
    }
    __syncthreads();
    float a=0.f; const float* wp = w2 + tid*16;
    #pragma unroll
    for (int j=0;j<16;j++) a += hid[j]*wp[j];
    scale[b*256+tid] = 1.f + sigmoidf_(a);
}

// ---------------- K3: base *= scale[b,c] ----------------
__global__ __launch_bounds__(256) void k_scale(float* __restrict__ base, const float* __restrict__ scale){
    int i = blockIdx.x*256+threadIdx.x;
    base[i] *= scale[i>>12];
}

// ---------------- K4: offset conv 3x3, 256->27, pad 1 ----------------
__global__ __launch_bounds__(256) void k_offconv(const float* __restrict__ base, const float* __restrict__ ow,
                                                 const float* __restrict__ ob, float* __restrict__ off){
    int bid = blockIdx.x;
    int b = bid>>4, tile = bid&15;
    int h0 = (tile>>2)<<4, w0 = (tile&3)<<4;
    int tid = threadIdx.x, ty = tid>>4, tx = tid&15;
    __shared__ float patch[18*18];
    float acc[27];
    #pragma unroll
    for (int ko=0;ko<27;ko++) acc[ko]=ob[ko];
    for (int c=0;c<CH;c++){
        const float* bp = base + ((size_t)(b*CH+c))*HWN;
        __syncthreads();
        for (int i=tid;i<324;i+=256){
            int py = h0 + i/18 - 1, px = w0 + (i%18) - 1;
            patch[i] = (py>=0&&py<HH&&px>=0&&px<WW)? bp[py*WW+px] : 0.f;
        }
        __syncthreads();
        float p[9];
        #pragma unroll
        for (int r=0;r<3;r++)
            #pragma unroll
            for (int s=0;s<3;s++) p[r*3+s]=patch[(ty+r)*18 + tx+s];
        const float* wp = ow + c*9;
        #pragma unroll
        for (int ko=0;ko<27;ko++){
            #pragma unroll
            for (int j=0;j<9;j++) acc[ko] += p[j]*wp[ko*CH*9 + j];
        }
    }
    int hw = (h0+ty)*WW + (w0+tx);
    #pragma unroll
    for (int ko=0;ko<27;ko++) off[((size_t)(b*27+ko))*HWN + hw] = acc[ko];
}

// ---------------- K5: DCNv2 sample + einsum -> enc (relu) ----------------
// block: 256 thr, handles (b,h): 64 positions x 64 output channels, K=2304 in 36 chunks of 64
__global__ __launch_bounds__(256) void k_dcn(const float* __restrict__ base, const float* __restrict__ off,
                                             const float* __restrict__ wT, const float* __restrict__ encb,
                                             float* __restrict__ enc){
    int bid = blockIdx.x;
    int b = bid>>6, h = bid&63;
    int tid = threadIdx.x;
    __shared__ float4 cw4[9*64];
    __shared__ int4   ci4[9*64];
    __shared__ float  smp[64*64];
    __shared__ float  wl[64*64];

    // phase A: per-(pos,k) corner indices/weights (mask folded in)
    for (int i=tid;i<576;i+=256){
        int p=i/9, k=i-9*p;
        const float* op = off + (size_t)b*27*HWN + h*WW + p;
        float dy = op[(2*k)*HWN];
        float dx = op[(2*k+1)*HWN];
        float m  = sigmoidf_(op[(18+k)*HWN]);
        float py = (float)(h + k/3 - 1) + dy;
        float px = (float)(p + (k%3) - 1) + dx;
        float y0 = floorf(py), x0 = floorf(px);
        float fy1 = py - y0, fy0 = 1.f - fy1;
        float fx1 = px - x0, fx0 = 1.f - fx1;
        int iy0 = (int)y0, ix0 = (int)x0;
        bool vy0 = (y0>=0.f)&&(y0<64.f), vy1 = (y0>=-1.f)&&(y0<63.f);
        bool vx0 = (x0>=0.f)&&(x0<64.f), vx1 = (x0>=-1.f)&&(x0<63.f);
        int cy0 = min(max(iy0,0),63), cy1 = min(max(iy0+1,0),63);
        int cx0 = min(max(ix0,0),63), cx1 = min(max(ix0+1,0),63);
        float4 wv; int4 iv;
        wv.x = (vy0&&vx0)? fy0*fx0*m : 0.f;
        wv.y = (vy0&&vx1)? fy0*fx1*m : 0.f;
        wv.z = (vy1&&vx0)? fy1*fx0*m : 0.f;
        wv.w = (vy1&&vx1)? fy1*fx1*m : 0.f;
        iv.x = cy0*WW+cx0; iv.y = cy0*WW+cx1; iv.z = cy1*WW+cx0; iv.w = cy1*WW+cx1;
        cw4[k*64+p]=wv; ci4[k*64+p]=iv;
    }

    float4 acc0=make_float4(0,0,0,0), acc1=acc0, acc2=acc0, acc3=acc0;
    int o4 = (tid&15)<<2, p4 = (tid>>4)<<2;
    int pos = tid&63, tg = tid>>6;
    const float* bb = base + (size_t)b*CH*HWN;

    for (int t=0;t<36;t++){
        __syncthreads();
        { // stage weight chunk
            const float4* wsrc = (const float4*)(wT + t*4096);
            float4* wdst = (float4*)wl;
            for (int i=tid;i<1024;i+=256) wdst[i] = wsrc[i];
        }
        // compute sample chunk: smp[ckl][pos]
        #pragma unroll
        for (int i=0;i<16;i++){
            int ckl = tg*16+i;
            int ckg = t*64+ckl;
            int c = ckg/9, k = ckg-9*c;
            float4 w = cw4[k*64+pos];
            int4  ix = ci4[k*64+pos];
            const float* bp = bb + (size_t)c*HWN;
            smp[ckl*64+pos] = w.x*bp[ix.x] + w.y*bp[ix.y] + w.z*bp[ix.z] + w.w*bp[ix.w];
        }
        __syncthreads();
        #pragma unroll 8
        for (int ckl=0;ckl<64;ckl++){
            float4 w4 = *(const float4*)(wl + ckl*64 + o4);
            float4 s4 = *(const float4*)(smp + ckl*64 + p4);
            acc0.x += w4.x*s4.x; acc0.y += w4.x*s4.y; acc0.z += w4.x*s4.z; acc0.w += w4.x*s4.w;
            acc1.x += w4.y*s4.x; acc1.y += w4.y*s4.y; acc1.z += w4.y*s4.z; acc1.w += w4.y*s4.w;
            acc2.x += w4.z*s4.x; acc2.y += w4.z*s4.y; acc2.z += w4.z*s4.z; acc2.w += w4.z*s4.w;
            acc3.x += w4.w*s4.x; acc3.y += w4.w*s4.y; acc3.z += w4.w*s4.z; acc3.w += w4.w*s4.w;
        }
    }
    // store
    #pragma unroll
    for (int i=0;i<4;i++){
        int o = o4+i;
        float bias = encb[o];
        float4 a = (i==0)?acc0:((i==1)?acc1:((i==2)?acc2:acc3));
        float4 r;
        r.x = fmaxf(a.x+bias,0.f); r.y = fmaxf(a.y+bias,0.f);
        r.z = fmaxf(a.z+bias,0.f); r.w = fmaxf(a.w+bias,0.f);
        *(float4*)(enc + ((size_t)(b*CCH+o))*HWN + h*WW + p4) = r;
    }
}

// ---------------- K6: two 3x3 convs (64->256) + BN + sigmoid + blend ----------------
__global__ __launch_bounds__(256) void k_fuse(const float* __restrict__ enc,
    const float* __restrict__ wew, const float* __restrict__ web, const float* __restrict__ weg,
    const float* __restrict__ webt, const float* __restrict__ wem, const float* __restrict__ wev,
    const float* __restrict__ wfw, const float* __restrict__ wfb, const float* __restrict__ wfg,
    const float* __restrict__ wfbt, const float* __restrict__ wfm, const float* __restrict__ wfv,
    const float* __restrict__ x, const float* __restrict__ y, float* __restrict__ out){
    int bid = blockIdx.x;
    int ocg = bid&7, tile = (bid>>3)&15, b = bid>>7;
    int h0 = (tile>>2)<<4, w0 = (tile&3)<<4;
    int tid = threadIdx.x, ty = tid>>4, tx = tid&15;
    __shared__ float patch[18*18];
    float acce[32], accf[32];
    #pragma unroll
    for (int i=0;i<32;i++){ acce[i]=web[ocg*32+i]; accf[i]=wfb[ocg*32+i]; }
    for (int c=0;c<CCH;c++){
        const float* ep = enc + ((size_t)(b*CCH+c))*HWN;
        __syncthreads();
        for (int i=tid;i<324;i+=256){
            int py = h0 + i/18 - 1, px = w0 + (i%18) - 1;
            patch[i] = (py>=0&&py<HH&&px>=0&&px<WW)? ep[py*WW+px] : 0.f;
        }
        __syncthreads();
        float p[9];
        #pragma unroll
        for (int r=0;r<3;r++)
            #pragma unroll
            for (int s=0;s<3;s++) p[r*3+s]=patch[(ty+r)*18 + tx+s];
        #pragma unroll
        for (int oc=0;oc<32;oc++){
            int o = ocg*32+oc;
            const float* wep = wew + ((size_t)o*CCH+c)*9;
            const float* wfp = wfw + ((size_t)o*CCH+c)*9;
            #pragma unroll
            for (int j=0;j<9;j++){ acce[oc] += p[j]*wep[j]; accf[oc] += p[j]*wfp[j]; }
        }
    }
    int hw = (h0+ty)*WW + (w0+tx);
    #pragma unroll
    for (int oc=0;oc<32;oc++){
        int o = ocg*32+oc;
        float inve = weg[o]*rsqrtf(wev[o]+1e-5f);
        float she  = webt[o]-wem[o]*inve;
        float invf = wfg[o]*rsqrtf(wfv[o]+1e-5f);
        float shf  = wfbt[o]-wfm[o]*invf;
        float ve = sigmoidf_(acce[oc]*inve+she);
        float vf = sigmoidf_(accf[oc]*invf+shf);
        size_t oi = ((size_t)(b*CH+o))*HWN + hw;
        out[oi] = ve*x[oi] + vf*y[oi];
    }
}

extern "C" void kernel_launch(void* const* d_in, const int* in_sizes, int n_in,
                              void* d_out, int out_size, void* d_ws, size_t ws_size,
                              hipStream_t stream) {
    const float* x     = (const float*)d_in[0];
    const float* y     = (const float*)d_in[1];
    const float* se_w1 = (const float*)d_in[2];
    const float* se_w2 = (const float*)d_in[3];
    const float* off_w = (const float*)d_in[4];
    const float* off_b = (const float*)d_in[5];
    const float* enc_w = (const float*)d_in[6];
    const float* enc_b = (const float*)d_in[7];
    const float* we_w  = (const float*)d_in[8];
    const float* we_b  = (const float*)d_in[9];
    const float* we_g  = (const float*)d_in[10];
    const float* we_bt = (const float*)d_in[11];
    const float* we_m  = (const float*)d_in[12];
    const float* we_v  = (const float*)d_in[13];
    const float* wf_w  = (const float*)d_in[14];
    const float* wf_b  = (const float*)d_in[15];
    const float* wf_g  = (const float*)d_in[16];
    const float* wf_bt = (const float*)d_in[17];
    const float* wf_m  = (const float*)d_in[18];
    const float* wf_v  = (const float*)d_in[19];
    float* out = (float*)d_out;

    float* ws    = (float*)d_ws;
    float* base  = ws;                       // 4*256*4096 = 4194304
    float* off   = base + 4194304;           // 4*27*4096  = 442368
    float* enc   = off  + 442368;            // 4*64*4096  = 1048576
    float* sums  = enc  + 1048576;           // 1024
    float* scale = sums + 1024;              // 1024
    float* wT    = scale+ 1024;              // 2304*64    = 147456

    k_wt      <<<576,  256, 0, stream>>>(enc_w, wT);
    k_base_sum<<<1024, 256, 0, stream>>>(x, y, base, sums);
    k_se      <<<4,    256, 0, stream>>>(sums, se_w1, se_w2, scale);
    k_scale   <<<16384,256, 0, stream>>>(base, scale);
    k_offconv <<<64,   256, 0, stream>>>(base, off_w, off_b, off);
    k_dcn     <<<256,  256, 0, stream>>>(base, off, wT, enc_b, enc);
    k_fuse    <<<512,  256, 0, stream>>>(enc, we_w, we_b, we_g, we_bt, we_m, we_v,
                                         wf_w, wf_b, wf_g, wf_bt, wf_m, wf_v, x, y, out);
}

// Round 4
// 731.708 us; speedup vs baseline: 2.5920x; 2.5920x over previous
//
#include <hip/hip_runtime.h>
#include <math.h>

#define BB 4
#define CH 256
#define CCH 64
#define HH 64
#define WW 64
#define HWN 4096

__device__ __forceinline__ float sigmoidf_(float v){ return 1.0f/(1.0f+__expf(-v)); }

// ---------------- K0: transpose enc_w (64,2304) -> wT (2304,64) ----------------
__global__ __launch_bounds__(256) void k_wt(const float* __restrict__ w, float* __restrict__ wT){
    int i = blockIdx.x*256 + threadIdx.x;
    if (i < 2304*64){ int ck = i>>6, o = i&63; wT[i] = w[o*2304 + ck]; }
}

// ---------------- K1: base = x+y, per-(b,c) sum ----------------
__global__ __launch_bounds__(256) void k_base_sum(const float* __restrict__ x, const float* __restrict__ y,
                                                  float* __restrict__ base, float* __restrict__ sums){
    int bc = blockIdx.x, tid = threadIdx.x;
    const float* xp = x + (size_t)bc*HWN;
    const float* yp = y + (size_t)bc*HWN;
    float* bp = base + (size_t)bc*HWN;
    float s = 0.f;
    for (int i=tid;i<HWN;i+=256){ float v = xp[i]+yp[i]; bp[i]=v; s+=v; }
    __shared__ float red[256];
    red[tid]=s; __syncthreads();
    for (int off=128; off>0; off>>=1){ if (tid<off) red[tid]+=red[tid+off]; __syncthreads(); }
    if (tid==0) sums[bc]=red[0];
}

// ---------------- K2: SE MLP -> scale = 1 + sigmoid(relu(mean@w1T)@w2T) ----------------
__global__ __launch_bounds__(256) void k_se(const float* __restrict__ sums, const float* __restrict__ w1,
                                            const float* __restrict__ w2, float* __restrict__ scale){
    int b = blockIdx.x, tid = threadIdx.x;
    __shared__ float sm[256];
    __shared__ float hid[16];
    sm[tid] = sums[b*256+tid]*(1.0f/4096.0f);
    __syncthreads();
    if (tid<16){
        float a=0.f; const float* wp = w1 + tid*256;
        for (int c=0;c<256;c++) a += sm[c]*wp[c];
        hid[tid]=fmaxf(a,0.f);
    }
    __syncthreads();
    float a=0.f; const float* wp = w2 + tid*16;
    #pragma unroll
    for (int j=0;j<16;j++) a += hid[j]*wp[j];
    scale[b*256+tid] = 1.f + sigmoidf_(a);
}

// ---------------- K3: base *= scale[b,c] ----------------
__global__ __launch_bounds__(256) void k_scale(float* __restrict__ base, const float* __restrict__ scale){
    int i = blockIdx.x*256+threadIdx.x;
    base[i] *= scale[i>>12];
}

// ---------------- K4a: offset conv partials — 8 channel-groups of 32 ----------------
// grid: b(4) x tile(16) x cg(8) = 512 blocks
__global__ __launch_bounds__(256) void k_offconv_part(const float* __restrict__ base, const float* __restrict__ ow,
                                                      float* __restrict__ part){
    int bid = blockIdx.x;
    int cg = bid&7, tile = (bid>>3)&15, b = bid>>7;
    int h0 = (tile>>2)<<4, w0 = (tile&3)<<4;
    int tid = threadIdx.x, ty = tid>>4, tx = tid&15;
    __shared__ float patch[18*18];
    float acc[27];
    #pragma unroll
    for (int ko=0;ko<27;ko++) acc[ko]=0.f;
    int c0 = cg<<5;
    for (int c=c0;c<c0+32;c++){
        const float* bp = base + ((size_t)(b*CH+c))*HWN;
        __syncthreads();
        for (int i=tid;i<324;i+=256){
            int py = h0 + i/18 - 1, px = w0 + (i%18) - 1;
            patch[i] = (py>=0&&py<HH&&px>=0&&px<WW)? bp[py*WW+px] : 0.f;
        }
        __syncthreads();
        float p[9];
        #pragma unroll
        for (int r=0;r<3;r++)
            #pragma unroll
            for (int s=0;s<3;s++) p[r*3+s]=patch[(ty+r)*18 + tx+s];
        const float* wp = ow + c*9;
        #pragma unroll
        for (int ko=0;ko<27;ko++){
            #pragma unroll
            for (int j=0;j<9;j++) acc[ko] += p[j]*wp[ko*CH*9 + j];
        }
    }
    int hw = (h0+ty)*WW + (w0+tx);
    #pragma unroll
    for (int ko=0;ko<27;ko++) part[((size_t)((cg*BB+b)*27+ko))*HWN + hw] = acc[ko];
}

// ---------------- K4b: reduce 8 partials + bias -> off ----------------
__global__ __launch_bounds__(256) void k_offreduce(const float* __restrict__ part, const float* __restrict__ ob,
                                                   float* __restrict__ off){
    int i = blockIdx.x*256+threadIdx.x;   // i < 4*27*4096
    int ko = (i>>12)%27;
    float s = ob[ko];
    #pragma unroll
    for (int cg=0;cg<8;cg++) s += part[(size_t)cg*442368 + i];
    off[i] = s;
}

// ---------------- K5: DCNv2 sample + einsum -> enc (relu), 512 threads ----------------
// block: 512 thr, handles (b,h): 64 positions x 64 output channels, K=2304 in 36 chunks of 64
__global__ __launch_bounds__(512) void k_dcn(const float* __restrict__ base, const float* __restrict__ off,
                                             const float* __restrict__ wT, const float* __restrict__ encb,
                                             float* __restrict__ enc){
    int bid = blockIdx.x;
    int b = bid>>6, h = bid&63;
    int tid = threadIdx.x;
    __shared__ float4 cw4[9*64];
    __shared__ int4   ci4[9*64];
    __shared__ float  smp[64*64];
    __shared__ float  wl[64*64];

    // phase A: per-(pos,k) corner indices/weights (mask folded in)
    for (int i=tid;i<576;i+=512){
        int p=i/9, k=i-9*p;
        const float* op = off + (size_t)b*27*HWN + h*WW + p;
        float dy = op[(2*k)*HWN];
        float dx = op[(2*k+1)*HWN];
        float m  = sigmoidf_(op[(18+k)*HWN]);
        float py = (float)(h + k/3 - 1) + dy;
        float px = (float)(p + (k%3) - 1) + dx;
        float y0 = floorf(py), x0 = floorf(px);
        float fy1 = py - y0, fy0 = 1.f - fy1;
        float fx1 = px - x0, fx0 = 1.f - fx1;
        int iy0 = (int)y0, ix0 = (int)x0;
        bool vy0 = (y0>=0.f)&&(y0<64.f), vy1 = (y0>=-1.f)&&(y0<63.f);
        bool vx0 = (x0>=0.f)&&(x0<64.f), vx1 = (x0>=-1.f)&&(x0<63.f);
        int cy0 = min(max(iy0,0),63), cy1 = min(max(iy0+1,0),63);
        int cx0 = min(max(ix0,0),63), cx1 = min(max(ix0+1,0),63);
        float4 wv; int4 iv;
        wv.x = (vy0&&vx0)? fy0*fx0*m : 0.f;
        wv.y = (vy0&&vx1)? fy0*fx1*m : 0.f;
        wv.z = (vy1&&vx0)? fy1*fx0*m : 0.f;
        wv.w = (vy1&&vx1)? fy1*fx1*m : 0.f;
        iv.x = cy0*WW+cx0; iv.y = cy0*WW+cx1; iv.z = cy1*WW+cx0; iv.w = cy1*WW+cx1;
        cw4[k*64+p]=wv; ci4[k*64+p]=iv;
    }

    float4 accA=make_float4(0,0,0,0), accB=accA;
    int o2 = (tid&31)<<1, p4 = (tid>>5)<<2;
    int pos = tid&63, sgrp = tid>>6;
    const float* bb = base + (size_t)b*CH*HWN;

    for (int t=0;t<36;t++){
        __syncthreads();
        { // stage weight chunk
            const float4* wsrc = (const float4*)(wT + t*4096);
            float4* wdst = (float4*)wl;
            for (int i=tid;i<1024;i+=512) wdst[i] = wsrc[i];
        }
        // compute sample chunk: smp[ckl][pos]
        #pragma unroll
        for (int i=0;i<8;i++){
            int ckl = sgrp*8+i;
            int ckg = t*64+ckl;
            int c = ckg/9, k = ckg-9*c;
            float4 w = cw4[k*64+pos];
            int4  ix = ci4[k*64+pos];
            const float* bp = bb + (size_t)c*HWN;
            smp[ckl*64+pos] = w.x*bp[ix.x] + w.y*bp[ix.y] + w.z*bp[ix.z] + w.w*bp[ix.w];
        }
        __syncthreads();
        #pragma unroll 8
        for (int ckl=0;ckl<64;ckl++){
            float2 w2 = *(const float2*)(wl + ckl*64 + o2);
            float4 s4 = *(const float4*)(smp + ckl*64 + p4);
            accA.x += w2.x*s4.x; accA.y += w2.x*s4.y; accA.z += w2.x*s4.z; accA.w += w2.x*s4.w;
            accB.x += w2.y*s4.x; accB.y += w2.y*s4.y; accB.z += w2.y*s4.z; accB.w += w2.y*s4.w;
        }
    }
    // store 2 oc x 4 pos
    {
        float biasA = encb[o2], biasB = encb[o2+1];
        float4 rA, rB;
        rA.x = fmaxf(accA.x+biasA,0.f); rA.y = fmaxf(accA.y+biasA,0.f);
        rA.z = fmaxf(accA.z+biasA,0.f); rA.w = fmaxf(accA.w+biasA,0.f);
        rB.x = fmaxf(accB.x+biasB,0.f); rB.y = fmaxf(accB.y+biasB,0.f);
        rB.z = fmaxf(accB.z+biasB,0.f); rB.w = fmaxf(accB.w+biasB,0.f);
        *(float4*)(enc + ((size_t)(b*CCH+o2  ))*HWN + h*WW + p4) = rA;
        *(float4*)(enc + ((size_t)(b*CCH+o2+1))*HWN + h*WW + p4) = rB;
    }
}

// ---------------- K6: two 3x3 convs (64->256) + BN + sigmoid + blend ----------------
// grid: b(4) x tile(16) x ocg(16) = 1024 blocks, 16 oc per block
__global__ __launch_bounds__(256) void k_fuse(const float* __restrict__ enc,
    const float* __restrict__ wew, const float* __restrict__ web, const float* __restrict__ weg,
    const float* __restrict__ webt, const float* __restrict__ wem, const float* __restrict__ wev,
    const float* __restrict__ wfw, const float* __restrict__ wfb, const float* __restrict__ wfg,
    const float* __restrict__ wfbt, const float* __restrict__ wfm, const float* __restrict__ wfv,
    const float* __restrict__ x, const float* __restrict__ y, float* __restrict__ out){
    int bid = blockIdx.x;
    int ocg = bid&15, tile = (bid>>4)&15, b = bid>>8;
    int h0 = (tile>>2)<<4, w0 = (tile&3)<<4;
    int tid = threadIdx.x, ty = tid>>4, tx = tid&15;
    __shared__ float patch[18*18];
    float acce[16], accf[16];
    #pragma unroll
    for (int i=0;i<16;i++){ acce[i]=web[ocg*16+i]; accf[i]=wfb[ocg*16+i]; }
    for (int c=0;c<CCH;c++){
        const float* ep = enc + ((size_t)(b*CCH+c))*HWN;
        __syncthreads();
        for (int i=tid;i<324;i+=256){
            int py = h0 + i/18 - 1, px = w0 + (i%18) - 1;
            patch[i] = (py>=0&&py<HH&&px>=0&&px<WW)? ep[py*WW+px] : 0.f;
        }
        __syncthreads();
        float p[9];
        #pragma unroll
        for (int r=0;r<3;r++)
            #pragma unroll
            for (int s=0;s<3;s++) p[r*3+s]=patch[(ty+r)*18 + tx+s];
        #pragma unroll
        for (int oc=0;oc<16;oc++){
            int o = ocg*16+oc;
            const float* wep = wew + ((size_t)o*CCH+c)*9;
            const float* wfp = wfw + ((size_t)o*CCH+c)*9;
            #pragma unroll
            for (int j=0;j<9;j++){ acce[oc] += p[j]*wep[j]; accf[oc] += p[j]*wfp[j]; }
        }
    }
    int hw = (h0+ty)*WW + (w0+tx);
    #pragma unroll
    for (int oc=0;oc<16;oc++){
        int o = ocg*16+oc;
        float inve = weg[o]*rsqrtf(wev[o]+1e-5f);
        float she  = webt[o]-wem[o]*inve;
        float invf = wfg[o]*rsqrtf(wfv[o]+1e-5f);
        float shf  = wfbt[o]-wfm[o]*invf;
        float ve = sigmoidf_(acce[oc]*inve+she);
        float vf = sigmoidf_(accf[oc]*invf+shf);
        size_t oi = ((size_t)(b*CH+o))*HWN + hw;
        out[oi] = ve*x[oi] + vf*y[oi];
    }
}

extern "C" void kernel_launch(void* const* d_in, const int* in_sizes, int n_in,
                              void* d_out, int out_size, void* d_ws, size_t ws_size,
                              hipStream_t stream) {
    const float* x     = (const float*)d_in[0];
    const float* y     = (const float*)d_in[1];
    const float* se_w1 = (const float*)d_in[2];
    const float* se_w2 = (const float*)d_in[3];
    const float* off_w = (const float*)d_in[4];
    const float* off_b = (const float*)d_in[5];
    const float* enc_w = (const float*)d_in[6];
    const float* enc_b = (const float*)d_in[7];
    const float* we_w  = (const float*)d_in[8];
    const float* we_b  = (const float*)d_in[9];
    const float* we_g  = (const float*)d_in[10];
    const float* we_bt = (const float*)d_in[11];
    const float* we_m  = (const float*)d_in[12];
    const float* we_v  = (const float*)d_in[13];
    const float* wf_w  = (const float*)d_in[14];
    const float* wf_b  = (const float*)d_in[15];
    const float* wf_g  = (const float*)d_in[16];
    const float* wf_bt = (const float*)d_in[17];
    const float* wf_m  = (const float*)d_in[18];
    const float* wf_v  = (const float*)d_in[19];
    float* out = (float*)d_out;

    float* ws    = (float*)d_ws;
    float* base  = ws;                       // 4*256*4096 = 4194304
    float* off   = base + 4194304;           // 4*27*4096  = 442368
    float* enc   = off  + 442368;            // 4*64*4096  = 1048576
    float* sums  = enc  + 1048576;           // 1024
    float* scale = sums + 1024;              // 1024
    float* wT    = scale+ 1024;              // 2304*64    = 147456
    float* part  = out;                      // reuse d_out as scratch: 8*4*27*4096 = 3538944 < 4194304

    k_wt          <<<576,  256, 0, stream>>>(enc_w, wT);
    k_base_sum    <<<1024, 256, 0, stream>>>(x, y, base, sums);
    k_se          <<<4,    256, 0, stream>>>(sums, se_w1, se_w2, scale);
    k_scale       <<<16384,256, 0, stream>>>(base, scale);
    k_offconv_part<<<512,  256, 0, stream>>>(base, off_w, part);
    k_offreduce   <<<1728, 256, 0, stream>>>(part, off_b, off);
    k_dcn         <<<256,  512, 0, stream>>>(base, off, wT, enc_b, enc);
    k_fuse        <<<1024, 256, 0, stream>>>(enc, we_w, we_b, we_g, we_bt, we_m, we_v,
                                             wf_w, wf_b, wf_g, wf_bt, wf_m, wf_v, x, y, out);
}

// Round 6
// 512.779 us; speedup vs baseline: 3.6987x; 1.4269x over previous
//
#include <hip/hip_runtime.h>
#include <math.h>

#define BB 4
#define CH 256
#define CCH 64
#define HH 64
#define WW 64
#define HWN 4096

typedef short s8v __attribute__((ext_vector_type(8)));
typedef float f4v __attribute__((ext_vector_type(4)));

__device__ __forceinline__ float sigmoidf_(float v){ return 1.0f/(1.0f+__expf(-v)); }
__device__ __forceinline__ unsigned short f2bf(float f){
    union{float f; unsigned u;} v; v.f=f;
    unsigned r = v.u + 0x7FFF + ((v.u>>16)&1);
    return (unsigned short)(r>>16);
}

// ---------------- K0: transpose enc_w (64,2304) -> wT (2304,64) ----------------
__global__ __launch_bounds__(256) void k_wt(const float* __restrict__ w, float* __restrict__ wT){
    int i = blockIdx.x*256 + threadIdx.x;
    if (i < 2304*64){ int ck = i>>6, o = i&63; wT[i] = w[o*2304 + ck]; }
}

// ---------------- K0b: gate weights -> bf16, K reordered tap-major: w2[row][j*64+ic] ----------------
__global__ __launch_bounds__(256) void k_wprep(const float* __restrict__ wew, const float* __restrict__ wfw,
                                               unsigned short* __restrict__ w2){
    int i = blockIdx.x*256+threadIdx.x;   // < 512*576
    if (i>=294912) return;
    int row = i/576, k = i-row*576;
    int j = k>>6, ic = k&63;
    float v = (row<256) ? wew[((row<<6)+ic)*9 + j] : wfw[(((row-256)<<6)+ic)*9 + j];
    w2[i] = f2bf(v);
}

// ---------------- K0c: fold conv-bias + BN into (inv, shift) per oc ----------------
__global__ __launch_bounds__(256) void k_bnprep(const float* __restrict__ web,const float* __restrict__ weg,
    const float* __restrict__ webt,const float* __restrict__ wem,const float* __restrict__ wev,
    const float* __restrict__ wfb,const float* __restrict__ wfg,const float* __restrict__ wfbt,
    const float* __restrict__ wfm,const float* __restrict__ wfv, float* __restrict__ bnp){
    int oc = threadIdx.x;
    float ie = weg[oc]*rsqrtf(wev[oc]+1e-5f);
    float se = webt[oc] - wem[oc]*ie + web[oc]*ie;
    float iff= wfg[oc]*rsqrtf(wfv[oc]+1e-5f);
    float sf = wfbt[oc] - wfm[oc]*iff + wfb[oc]*iff;
    *(float4*)(bnp + oc*4) = make_float4(ie, se, iff, sf);
}

// ---------------- K1: base = x+y, per-(b,c) sum ----------------
__global__ __launch_bounds__(256) void k_base_sum(const float* __restrict__ x, const float* __restrict__ y,
                                                  float* __restrict__ base, float* __restrict__ sums){
    int bc = blockIdx.x, tid = threadIdx.x;
    const float* xp = x + (size_t)bc*HWN;
    const float* yp = y + (size_t)bc*HWN;
    float* bp = base + (size_t)bc*HWN;
    float s = 0.f;
    for (int i=tid;i<HWN;i+=256){ float v = xp[i]+yp[i]; bp[i]=v; s+=v; }
    __shared__ float red[256];
    red[tid]=s; __syncthreads();
    for (int off=128; off>0; off>>=1){ if (tid<off) red[tid]+=red[tid+off]; __syncthreads(); }
    if (tid==0) sums[bc]=red[0];
}

// ---------------- K2: SE MLP -> scale = 1 + sigmoid(relu(mean@w1T)@w2T) ----------------
__global__ __launch_bounds__(256) void k_se(const float* __restrict__ sums, const float* __restrict__ w1,
                                            const float* __restrict__ w2, float* __restrict__ scale){
    int b = blockIdx.x, tid = threadIdx.x;
    __shared__ float sm[256];
    __shared__ float hid[16];
    sm[tid] = sums[b*256+tid]*(1.0f/4096.0f);
    __syncthreads();
    if (tid<16){
        float a=0.f; const float* wp = w1 + tid*256;
        for (int c=0;c<256;c++) a += sm[c]*wp[c];
        hid[tid]=fmaxf(a,0.f);
    }
    __syncthreads();
    float a=0.f; const float* wp = w2 + tid*16;
    #pragma unroll
    for (int j=0;j<16;j++) a += hid[j]*wp[j];
    scale[b*256+tid] = 1.f + sigmoidf_(a);
}

// ---------------- K3: base *= scale[b,c] ----------------
__global__ __launch_bounds__(256) void k_scale(float* __restrict__ base, const float* __restrict__ scale){
    int i = blockIdx.x*256+threadIdx.x;
    base[i] *= scale[i>>12];
}

// ---------------- K4a: offset conv partials — 8 channel-groups of 32 ----------------
__global__ __launch_bounds__(256) void k_offconv_part(const float* __restrict__ base, const float* __restrict__ ow,
                                                      float* __restrict__ part){
    int bid = blockIdx.x;
    int cg = bid&7, tile = (bid>>3)&15, b = bid>>7;
    int h0 = (tile>>2)<<4, w0 = (tile&3)<<4;
    int tid = threadIdx.x, ty = tid>>4, tx = tid&15;
    __shared__ float patch[18*18];
    float acc[27];
    #pragma unroll
    for (int ko=0;ko<27;ko++) acc[ko]=0.f;
    int c0 = cg<<5;
    for (int c=c0;c<c0+32;c++){
        const float* bp = base + ((size_t)(b*CH+c))*HWN;
        __syncthreads();
        for (int i=tid;i<324;i+=256){
            int py = h0 + i/18 - 1, px = w0 + (i%18) - 1;
            patch[i] = (py>=0&&py<HH&&px>=0&&px<WW)? bp[py*WW+px] : 0.f;
        }
        __syncthreads();
        float p[9];
        #pragma unroll
        for (int r=0;r<3;r++)
            #pragma unroll
            for (int s=0;s<3;s++) p[r*3+s]=patch[(ty+r)*18 + tx+s];
        const float* wp = ow + c*9;
        #pragma unroll
        for (int ko=0;ko<27;ko++){
            #pragma unroll
            for (int j=0;j<9;j++) acc[ko] += p[j]*wp[ko*CH*9 + j];
        }
    }
    int hw = (h0+ty)*WW + (w0+tx);
    #pragma unroll
    for (int ko=0;ko<27;ko++) part[((size_t)((cg*BB+b)*27+ko))*HWN + hw] = acc[ko];
}

// ---------------- K4b: reduce 8 partials + bias -> off ----------------
__global__ __launch_bounds__(256) void k_offreduce(const float* __restrict__ part, const float* __restrict__ ob,
                                                   float* __restrict__ off){
    int i = blockIdx.x*256+threadIdx.x;   // i < 4*27*4096
    int ko = (i>>12)%27;
    float s = ob[ko];
    #pragma unroll
    for (int cg=0;cg<8;cg++) s += part[(size_t)cg*442368 + i];
    off[i] = s;
}

// ---------------- K5: DCNv2 sample + einsum -> enc_t bf16 [b][pos][oc] (relu) ----------------
__global__ __launch_bounds__(512) void k_dcn(const float* __restrict__ base, const float* __restrict__ off,
                                             const float* __restrict__ wT, const float* __restrict__ encb,
                                             unsigned short* __restrict__ enc_t){
    int bid = blockIdx.x;
    int b = bid>>6, h = bid&63;
    int tid = threadIdx.x;
    __shared__ float4 cw4[9*64];
    __shared__ int4   ci4[9*64];
    __shared__ float  smp[64*64];
    __shared__ float  wl[64*64];

    for (int i=tid;i<576;i+=512){
        int p=i/9, k=i-9*p;
        const float* op = off + (size_t)b*27*HWN + h*WW + p;
        float dy = op[(2*k)*HWN];
        float dx = op[(2*k+1)*HWN];
        float m  = sigmoidf_(op[(18+k)*HWN]);
        float py = (float)(h + k/3 - 1) + dy;
        float px = (float)(p + (k%3) - 1) + dx;
        float y0 = floorf(py), x0 = floorf(px);
        float fy1 = py - y0, fy0 = 1.f - fy1;
        float fx1 = px - x0, fx0 = 1.f - fx1;
        int iy0 = (int)y0, ix0 = (int)x0;
        bool vy0 = (y0>=0.f)&&(y0<64.f), vy1 = (y0>=-1.f)&&(y0<63.f);
        bool vx0 = (x0>=0.f)&&(x0<64.f), vx1 = (x0>=-1.f)&&(x0<63.f);
        int cy0 = min(max(iy0,0),63), cy1 = min(max(iy0+1,0),63);
        int cx0 = min(max(ix0,0),63), cx1 = min(max(ix0+1,0),63);
        float4 wv; int4 iv;
        wv.x = (vy0&&vx0)? fy0*fx0*m : 0.f;
        wv.y = (vy0&&vx1)? fy0*fx1*m : 0.f;
        wv.z = (vy1&&vx0)? fy1*fx0*m : 0.f;
        wv.w = (vy1&&vx1)? fy1*fx1*m : 0.f;
        iv.x = cy0*WW+cx0; iv.y = cy0*WW+cx1; iv.z = cy1*WW+cx0; iv.w = cy1*WW+cx1;
        cw4[k*64+p]=wv; ci4[k*64+p]=iv;
    }

    float4 accA=make_float4(0,0,0,0), accB=accA;
    int o2 = (tid&31)<<1, p4 = (tid>>5)<<2;
    int pos = tid&63, sgrp = tid>>6;
    const float* bb = base + (size_t)b*CH*HWN;

    for (int t=0;t<36;t++){
        __syncthreads();
        {
            const float4* wsrc = (const float4*)(wT + t*4096);
            float4* wdst = (float4*)wl;
            for (int i=tid;i<1024;i+=512) wdst[i] = wsrc[i];
        }
        #pragma unroll
        for (int i=0;i<8;i++){
            int ckl = sgrp*8+i;
            int ckg = t*64+ckl;
            int c = ckg/9, k = ckg-9*c;
            float4 w = cw4[k*64+pos];
            int4  ix = ci4[k*64+pos];
            const float* bp = bb + (size_t)c*HWN;
            smp[ckl*64+pos] = w.x*bp[ix.x] + w.y*bp[ix.y] + w.z*bp[ix.z] + w.w*bp[ix.w];
        }
        __syncthreads();
        #pragma unroll 8
        for (int ckl=0;ckl<64;ckl++){
            float2 w2 = *(const float2*)(wl + ckl*64 + o2);
            float4 s4 = *(const float4*)(smp + ckl*64 + p4);
            accA.x += w2.x*s4.x; accA.y += w2.x*s4.y; accA.z += w2.x*s4.z; accA.w += w2.x*s4.w;
            accB.x += w2.y*s4.x; accB.y += w2.y*s4.y; accB.z += w2.y*s4.z; accB.w += w2.y*s4.w;
        }
    }
    // store bf16, [b][pos][oc] layout, 2 oc x 4 pos per thread
    {
        float biasA = encb[o2], biasB = encb[o2+1];
        unsigned short* et = enc_t + (((size_t)b<<12) + h*WW)*64;
        float ra[4] = {accA.x,accA.y,accA.z,accA.w};
        float rb[4] = {accB.x,accB.y,accB.z,accB.w};
        #pragma unroll
        for (int i=0;i<4;i++){
            unsigned short lo = f2bf(fmaxf(ra[i]+biasA,0.f));
            unsigned short hi = f2bf(fmaxf(rb[i]+biasB,0.f));
            unsigned int packed = (unsigned int)lo | ((unsigned int)hi<<16);
            *(unsigned int*)(et + (size_t)(p4+i)*64 + o2) = packed;
        }
    }
}

// ---------------- K6: fused gate convs via MFMA bf16 + BN + sigmoid + blend ----------------
// grid: b(4) x tile(16) x ocg(4) = 256 blocks, 512 thr (8 waves)
// block: C[128 rows][256 pos], rows = 64 we-oc ++ same 64 wf-oc; K=576 (tap-major)
__global__ __launch_bounds__(512) void k_fuse_mfma(const unsigned short* __restrict__ enc_t,
    const unsigned short* __restrict__ w2, const float* __restrict__ bnp,
    const float* __restrict__ x, const float* __restrict__ y, float* __restrict__ out){
    int bid = blockIdx.x;
    int ocg = bid&3, tile = (bid>>2)&15, b = bid>>6;
    int h0 = (tile>>2)<<4, w0 = (tile&3)<<4;
    int tid = threadIdx.x;
    __shared__ unsigned short elds[324*64];   // 41472 B, 16B-chunk XOR swizzle

    // stage 18x18 halo x 64ch, channel-contiguous; swizzle chunk ^= sp&7
    const unsigned short* ebase = enc_t + (((size_t)b)<<12)*64;
    #pragma unroll
    for (int kk=0;kk<6;kk++){
        int i = tid + kk*512;
        if (i < 2592){
            int sp = i>>3, icg = i&7;
            int sy = sp/18, sx = sp - sy*18;
            int py = h0+sy-1, px = w0+sx-1;
            uint4 v = make_uint4(0u,0u,0u,0u);
            if (py>=0 && py<HH && px>=0 && px<WW)
                v = *(const uint4*)(ebase + (size_t)((py<<6)+px)*64 + (icg<<3));
            int chunk = ((sp<<3) | icg) ^ (sp&7);
            *(uint4*)(elds + (chunk<<3)) = v;
        }
    }
    __syncthreads();

    int lane = tid&63, w = tid>>6;
    int col = lane&15, kg = lane>>4;
    f4v acc[8][2];
    #pragma unroll
    for (int rf=0;rf<8;rf++)
        #pragma unroll
        for (int pf=0;pf<2;pf++) acc[rf][pf] = (f4v){0.f,0.f,0.f,0.f};

    #pragma unroll
    for (int t=0;t<18;t++){
        const int j = t>>1, ih = t&1;
        const int dy = j/3-1, dx = j%3-1;
        s8v af[8];
        #pragma unroll
        for (int rf=0;rf<8;rf++){
            int row = (rf<4 ? ocg*64 + rf*16 : 256 + ocg*64 + (rf-4)*16) + col;
            af[rf] = *(const s8v*)(w2 + (size_t)row*576 + t*32 + kg*8);
        }
        s8v bfr[2];
        #pragma unroll
        for (int pf=0;pf<2;pf++){
            int tyc = w*2+pf;
            int sp = (tyc+dy+1)*18 + (col+dx+1);
            int chunk = ((sp<<3) | (ih*4+kg)) ^ (sp&7);
            bfr[pf] = *(const s8v*)(elds + (chunk<<3));
        }
        #pragma unroll
        for (int rf=0;rf<8;rf++)
            #pragma unroll
            for (int pf=0;pf<2;pf++)
                acc[rf][pf] = __builtin_amdgcn_mfma_f32_16x16x32_bf16(af[rf], bfr[pf], acc[rf][pf], 0,0,0);
    }

    // epilogue: pair we-acc (rf) with wf-acc (rf+4), BN+sigmoid, blend
    #pragma unroll
    for (int rf=0;rf<4;rf++){
        #pragma unroll
        for (int pf=0;pf<2;pf++){
            int tyc = w*2+pf;
            int py = h0+tyc, px = w0+col;
            #pragma unroll
            for (int r=0;r<4;r++){
                int oc = ocg*64 + rf*16 + kg*4 + r;
                float4 bn = *(const float4*)(bnp + oc*4);
                float ve = sigmoidf_(acc[rf  ][pf][r]*bn.x + bn.y);
                float vf = sigmoidf_(acc[rf+4][pf][r]*bn.z + bn.w);
                size_t oi = (((size_t)((b<<8)+oc))<<12) + (py<<6) + px;
                out[oi] = ve*x[oi] + vf*y[oi];
            }
        }
    }
}

extern "C" void kernel_launch(void* const* d_in, const int* in_sizes, int n_in,
                              void* d_out, int out_size, void* d_ws, size_t ws_size,
                              hipStream_t stream) {
    const float* x     = (const float*)d_in[0];
    const float* y     = (const float*)d_in[1];
    const float* se_w1 = (const float*)d_in[2];
    const float* se_w2 = (const float*)d_in[3];
    const float* off_w = (const float*)d_in[4];
    const float* off_b = (const float*)d_in[5];
    const float* enc_w = (const float*)d_in[6];
    const float* enc_b = (const float*)d_in[7];
    const float* we_w  = (const float*)d_in[8];
    const float* we_b  = (const float*)d_in[9];
    const float* we_g  = (const float*)d_in[10];
    const float* we_bt = (const float*)d_in[11];
    const float* we_m  = (const float*)d_in[12];
    const float* we_v  = (const float*)d_in[13];
    const float* wf_w  = (const float*)d_in[14];
    const float* wf_b  = (const float*)d_in[15];
    const float* wf_g  = (const float*)d_in[16];
    const float* wf_bt = (const float*)d_in[17];
    const float* wf_m  = (const float*)d_in[18];
    const float* wf_v  = (const float*)d_in[19];
    float* out = (float*)d_out;

    float* ws     = (float*)d_ws;
    float* base   = ws;                       // 4194304 f
    float* off    = base + 4194304;           // 442368 f
    float* encT_f = off  + 442368;            // 524288 f  (= 1048576 ushort)
    float* sums   = encT_f + 524288;          // 1024 f
    float* scale  = sums + 1024;              // 1024 f
    float* wT     = scale+ 1024;              // 147456 f
    float* w2f    = wT   + 147456;            // 147456 f (= 294912 ushort)
    float* bnp    = w2f  + 147456;            // 1024 f
    unsigned short* enc_t = (unsigned short*)encT_f;
    unsigned short* w2    = (unsigned short*)w2f;
    float* part   = out;                      // d_out scratch: 3538944 < 4194304

    k_wt          <<<576,  256, 0, stream>>>(enc_w, wT);
    k_wprep       <<<1152, 256, 0, stream>>>(we_w, wf_w, w2);
    k_bnprep      <<<1,    256, 0, stream>>>(we_b, we_g, we_bt, we_m, we_v,
                                             wf_b, wf_g, wf_bt, wf_m, wf_v, bnp);
    k_base_sum    <<<1024, 256, 0, stream>>>(x, y, base, sums);
    k_se          <<<4,    256, 0, stream>>>(sums, se_w1, se_w2, scale);
    k_scale       <<<16384,256, 0, stream>>>(base, scale);
    k_offconv_part<<<512,  256, 0, stream>>>(base, off_w, part);
    k_offreduce   <<<1728, 256, 0, stream>>>(part, off_b, off);
    k_dcn         <<<256,  512, 0, stream>>>(base, off, wT, enc_b, enc_t);
    k_fuse_mfma   <<<256,  512, 0, stream>>>(enc_t, w2, bnp, x, y, out);
}

// Round 7
// 440.087 us; speedup vs baseline: 4.3097x; 1.1652x over previous
//
#include <hip/hip_runtime.h>
#include <math.h>

#define BB 4
#define CH 256
#define CCH 64
#define HH 64
#define WW 64
#define HWN 4096

typedef short s8v __attribute__((ext_vector_type(8)));
typedef float f4v __attribute__((ext_vector_type(4)));

__device__ __forceinline__ float sigmoidf_(float v){ return 1.0f/(1.0f+__expf(-v)); }
__device__ __forceinline__ unsigned short f2bf(float f){
    union{float f; unsigned u;} v; v.f=f;
    unsigned r = v.u + 0x7FFF + ((v.u>>16)&1);
    return (unsigned short)(r>>16);
}

// ---------------- K0a: enc_w -> bf16 (layout already [oc][ck=c*9+k]) ----------------
__global__ __launch_bounds__(256) void k_wdcn(const float* __restrict__ w, unsigned short* __restrict__ wd){
    int i = blockIdx.x*256 + threadIdx.x;
    if (i < 147456) wd[i] = f2bf(w[i]);
}

// ---------------- K0b: gate weights -> bf16, K reordered tap-major: w2[row][j*64+ic] ----------------
__global__ __launch_bounds__(256) void k_wprep(const float* __restrict__ wew, const float* __restrict__ wfw,
                                               unsigned short* __restrict__ w2){
    int i = blockIdx.x*256+threadIdx.x;   // < 512*576
    if (i>=294912) return;
    int row = i/576, k = i-row*576;
    int j = k>>6, ic = k&63;
    float v = (row<256) ? wew[((row<<6)+ic)*9 + j] : wfw[(((row-256)<<6)+ic)*9 + j];
    w2[i] = f2bf(v);
}

// ---------------- K0c: fold conv-bias + BN into (inv, shift) per oc ----------------
__global__ __launch_bounds__(256) void k_bnprep(const float* __restrict__ web,const float* __restrict__ weg,
    const float* __restrict__ webt,const float* __restrict__ wem,const float* __restrict__ wev,
    const float* __restrict__ wfb,const float* __restrict__ wfg,const float* __restrict__ wfbt,
    const float* __restrict__ wfm,const float* __restrict__ wfv, float* __restrict__ bnp){
    int oc = threadIdx.x;
    float ie = weg[oc]*rsqrtf(wev[oc]+1e-5f);
    float se = webt[oc] - wem[oc]*ie + web[oc]*ie;
    float iff= wfg[oc]*rsqrtf(wfv[oc]+1e-5f);
    float sf = wfbt[oc] - wfm[oc]*iff + wfb[oc]*iff;
    *(float4*)(bnp + oc*4) = make_float4(ie, se, iff, sf);
}

// ---------------- K1: base = x+y, per-(b,c) sum ----------------
__global__ __launch_bounds__(256) void k_base_sum(const float* __restrict__ x, const float* __restrict__ y,
                                                  float* __restrict__ base, float* __restrict__ sums){
    int bc = blockIdx.x, tid = threadIdx.x;
    const float* xp = x + (size_t)bc*HWN;
    const float* yp = y + (size_t)bc*HWN;
    float* bp = base + (size_t)bc*HWN;
    float s = 0.f;
    for (int i=tid;i<HWN;i+=256){ float v = xp[i]+yp[i]; bp[i]=v; s+=v; }
    __shared__ float red[256];
    red[tid]=s; __syncthreads();
    for (int off=128; off>0; off>>=1){ if (tid<off) red[tid]+=red[tid+off]; __syncthreads(); }
    if (tid==0) sums[bc]=red[0];
}

// ---------------- K2: SE MLP -> scale = 1 + sigmoid(relu(mean@w1T)@w2T) ----------------
__global__ __launch_bounds__(256) void k_se(const float* __restrict__ sums, const float* __restrict__ w1,
                                            const float* __restrict__ w2, float* __restrict__ scale){
    int b = blockIdx.x, tid = threadIdx.x;
    __shared__ float sm[256];
    __shared__ float hid[16];
    sm[tid] = sums[b*256+tid]*(1.0f/4096.0f);
    __syncthreads();
    if (tid<16){
        float a=0.f; const float* wp = w1 + tid*256;
        for (int c=0;c<256;c++) a += sm[c]*wp[c];
        hid[tid]=fmaxf(a,0.f);
    }
    __syncthreads();
    float a=0.f; const float* wp = w2 + tid*16;
    #pragma unroll
    for (int j=0;j<16;j++) a += hid[j]*wp[j];
    scale[b*256+tid] = 1.f + sigmoidf_(a);
}

// ---------------- K3: base *= scale[b,c] ----------------
__global__ __launch_bounds__(256) void k_scale(float* __restrict__ base, const float* __restrict__ scale){
    int i = blockIdx.x*256+threadIdx.x;
    base[i] *= scale[i>>12];
}

// ---------------- K4a: offset conv partials — 8 channel-groups of 32 ----------------
__global__ __launch_bounds__(256) void k_offconv_part(const float* __restrict__ base, const float* __restrict__ ow,
                                                      float* __restrict__ part){
    int bid = blockIdx.x;
    int cg = bid&7, tile = (bid>>3)&15, b = bid>>7;
    int h0 = (tile>>2)<<4, w0 = (tile&3)<<4;
    int tid = threadIdx.x, ty = tid>>4, tx = tid&15;
    __shared__ float patch[18*18];
    float acc[27];
    #pragma unroll
    for (int ko=0;ko<27;ko++) acc[ko]=0.f;
    int c0 = cg<<5;
    for (int c=c0;c<c0+32;c++){
        const float* bp = base + ((size_t)(b*CH+c))*HWN;
        __syncthreads();
        for (int i=tid;i<324;i+=256){
            int py = h0 + i/18 - 1, px = w0 + (i%18) - 1;
            patch[i] = (py>=0&&py<HH&&px>=0&&px<WW)? bp[py*WW+px] : 0.f;
        }
        __syncthreads();
        float p[9];
        #pragma unroll
        for (int r=0;r<3;r++)
            #pragma unroll
            for (int s=0;s<3;s++) p[r*3+s]=patch[(ty+r)*18 + tx+s];
        const float* wp = ow + c*9;
        #pragma unroll
        for (int ko=0;ko<27;ko++){
            #pragma unroll
            for (int j=0;j<9;j++) acc[ko] += p[j]*wp[ko*CH*9 + j];
        }
    }
    int hw = (h0+ty)*WW + (w0+tx);
    #pragma unroll
    for (int ko=0;ko<27;ko++) part[((size_t)((cg*BB+b)*27+ko))*HWN + hw] = acc[ko];
}

// ---------------- K4b: reduce 8 partials + bias -> off ----------------
__global__ __launch_bounds__(256) void k_offreduce(const float* __restrict__ part, const float* __restrict__ ob,
                                                   float* __restrict__ off){
    int i = blockIdx.x*256+threadIdx.x;   // i < 4*27*4096
    int ko = (i>>12)%27;
    float s = ob[ko];
    #pragma unroll
    for (int cg=0;cg<8;cg++) s += part[(size_t)cg*442368 + i];
    off[i] = s;
}

// ---------------- K5a: per-(b,k,pos) corner weights/indices ----------------
__global__ __launch_bounds__(256) void k_prep_off(const float* __restrict__ off,
                                                  float4* __restrict__ cwg, int4* __restrict__ cig){
    int i = blockIdx.x*256+threadIdx.x;   // < 4*9*4096
    if (i >= 147456) return;
    int b = i/36864, rem = i - b*36864;
    int k = rem>>12, pos = rem&4095;
    int h = pos>>6, p = pos&63;
    const float* op = off + ((size_t)b*27<<12) + pos;
    float dy = op[(size_t)(2*k)<<12];
    float dx = op[(size_t)(2*k+1)<<12];
    float m  = sigmoidf_(op[(size_t)(18+k)<<12]);
    float py = (float)(h + k/3 - 1) + dy;
    float px = (float)(p + (k%3) - 1) + dx;
    float y0 = floorf(py), x0 = floorf(px);
    float fy1 = py - y0, fy0 = 1.f - fy1;
    float fx1 = px - x0, fx0 = 1.f - fx1;
    int iy0 = (int)y0, ix0 = (int)x0;
    bool vy0 = (y0>=0.f)&&(y0<64.f), vy1 = (y0>=-1.f)&&(y0<63.f);
    bool vx0 = (x0>=0.f)&&(x0<64.f), vx1 = (x0>=-1.f)&&(x0<63.f);
    int cy0 = min(max(iy0,0),63), cy1 = min(max(iy0+1,0),63);
    int cx0 = min(max(ix0,0),63), cx1 = min(max(ix0+1,0),63);
    float4 wv; int4 iv;
    wv.x = (vy0&&vx0)? fy0*fx0*m : 0.f;
    wv.y = (vy0&&vx1)? fy0*fx1*m : 0.f;
    wv.z = (vy1&&vx0)? fy1*fx0*m : 0.f;
    wv.w = (vy1&&vx1)? fy1*fx1*m : 0.f;
    iv.x = cy0*WW+cx0; iv.y = cy0*WW+cx1; iv.z = cy1*WW+cx0; iv.w = cy1*WW+cx1;
    cwg[i] = wv; cig[i] = iv;
}

// ---------------- K5b: DCNv2 sample (bf16) + MFMA einsum, split-K x4 ----------------
// grid: cg(4) x h(64) x b(4) = 1024 blocks, 512 thr (8 waves)
// block: C-partial[64 oc][64 pos] over K = 576 (c in [cg*64, cg*64+64))
__global__ __launch_bounds__(512,4) void k_dcn_mfma(const float* __restrict__ base,
    const float4* __restrict__ cwg, const int4* __restrict__ cig,
    const unsigned short* __restrict__ wdcn, float* __restrict__ part2){
    int bid = blockIdx.x;
    int cg = bid&3, h = (bid>>2)&63, b = bid>>8;
    int tid = threadIdx.x;
    __shared__ float4 cw4[576];
    __shared__ int4   ci4[576];
    __shared__ unsigned short smp[64*64];  // [pos][64 ck] bf16 as 16B chunks, XOR swizzled

    for (int i=tid;i<576;i+=512){
        cw4[i] = cwg[(((size_t)b*9 + (i>>6))<<12) + (h<<6) + (i&63)];
        ci4[i] = cig[(((size_t)b*9 + (i>>6))<<12) + (h<<6) + (i&63)];
    }
    __syncthreads();

    int pos = tid&63, sgrp = tid>>6;
    int w = tid>>6, lane = tid&63;
    int mf = w&3, nh = w>>2;
    int col = lane&15, kg = lane>>4;
    f4v acc0 = (f4v){0.f,0.f,0.f,0.f}, acc1 = acc0;
    const float* bb = base + ((size_t)b*CH + cg*64)*HWN;

    for (int t=0;t<9;t++){
        unsigned int pk[4];
        #pragma unroll
        for (int i=0;i<8;i++){
            int ckL = t*64 + sgrp*8 + i;           // 0..575 local
            int c = ckL/9, k = ckL - 9*c;          // c local 0..63
            float4 wv = cw4[k*64+pos];
            int4  iv = ci4[k*64+pos];
            const float* bp = bb + (size_t)c*HWN;
            float v = wv.x*bp[iv.x] + wv.y*bp[iv.y] + wv.z*bp[iv.z] + wv.w*bp[iv.w];
            unsigned short us = f2bf(v);
            if (i&1) pk[i>>1] |= ((unsigned)us)<<16; else pk[i>>1] = (unsigned)us;
        }
        __syncthreads();   // previous chunk's MFMA reads done
        {
            int chunk = (pos<<3) | (sgrp ^ (pos&7));
            *(uint4*)(smp + (chunk<<3)) = *(const uint4*)pk;
        }
        __syncthreads();
        #pragma unroll
        for (int ks=0;ks<2;ks++){
            int koff = cg*576 + t*64 + ks*32 + kg*8;
            s8v a = *(const s8v*)(wdcn + (size_t)(mf*16+col)*2304 + koff);
            int cgrp = ks*4+kg;
            int p0 = (nh*2)*16 + col;
            int p1 = (nh*2+1)*16 + col;
            s8v b0 = *(const s8v*)(smp + (((p0<<3)|(cgrp^(p0&7)))<<3));
            s8v b1 = *(const s8v*)(smp + (((p1<<3)|(cgrp^(p1&7)))<<3));
            acc0 = __builtin_amdgcn_mfma_f32_16x16x32_bf16(a, b0, acc0, 0,0,0);
            acc1 = __builtin_amdgcn_mfma_f32_16x16x32_bf16(a, b1, acc1, 0,0,0);
        }
    }
    // partial write: part2[cg][b][pos_g][oc]
    float* pout = part2 + ((size_t)(cg*BB + b))*(HWN*64);
    #pragma unroll
    for (int j=0;j<2;j++){
        f4v a = j ? acc1 : acc0;
        int posg = (h<<6) + (nh*2+j)*16 + col;
        int oc = mf*16 + kg*4;
        *(float4*)(pout + (size_t)posg*64 + oc) = *(float4*)&a;
    }
}

// ---------------- K5c: sum 4 partials + bias + relu -> enc_t bf16 [b][pos][oc] ----------------
__global__ __launch_bounds__(256) void k_encreduce(const float* __restrict__ part2, const float* __restrict__ encb,
                                                   unsigned short* __restrict__ enc_t){
    int i = blockIdx.x*256+threadIdx.x;   // < 4*4096*32
    int b = i>>17, rem = i&131071;
    int pos = rem>>5, oc2 = rem&31;
    size_t basei = (((size_t)b<<12) + pos)*64 + oc2*2;
    float s0 = encb[oc2*2], s1 = encb[oc2*2+1];
    #pragma unroll
    for (int cg=0;cg<4;cg++){
        const float* p = part2 + (size_t)cg*1048576 + basei;
        s0 += p[0]; s1 += p[1];
    }
    unsigned short lo = f2bf(fmaxf(s0,0.f));
    unsigned short hi = f2bf(fmaxf(s1,0.f));
    *(unsigned int*)(enc_t + basei) = (unsigned int)lo | ((unsigned int)hi<<16);
}

// ---------------- K6: fused gate convs via MFMA bf16 + BN + sigmoid + blend ----------------
__global__ __launch_bounds__(512) void k_fuse_mfma(const unsigned short* __restrict__ enc_t,
    const unsigned short* __restrict__ w2, const float* __restrict__ bnp,
    const float* __restrict__ x, const float* __restrict__ y, float* __restrict__ out){
    int bid = blockIdx.x;
    int ocg = bid&3, tile = (bid>>2)&15, b = bid>>6;
    int h0 = (tile>>2)<<4, w0 = (tile&3)<<4;
    int tid = threadIdx.x;
    __shared__ unsigned short elds[324*64];   // 41472 B, 16B-chunk XOR swizzle

    const unsigned short* ebase = enc_t + (((size_t)b)<<12)*64;
    #pragma unroll
    for (int kk=0;kk<6;kk++){
        int i = tid + kk*512;
        if (i < 2592){
            int sp = i>>3, icg = i&7;
            int sy = sp/18, sx = sp - sy*18;
            int py = h0+sy-1, px = w0+sx-1;
            uint4 v = make_uint4(0u,0u,0u,0u);
            if (py>=0 && py<HH && px>=0 && px<WW)
                v = *(const uint4*)(ebase + (size_t)((py<<6)+px)*64 + (icg<<3));
            int chunk = ((sp<<3) | icg) ^ (sp&7);
            *(uint4*)(elds + (chunk<<3)) = v;
        }
    }
    __syncthreads();

    int lane = tid&63, w = tid>>6;
    int col = lane&15, kg = lane>>4;
    f4v acc[8][2];
    #pragma unroll
    for (int rf=0;rf<8;rf++)
        #pragma unroll
        for (int pf=0;pf<2;pf++) acc[rf][pf] = (f4v){0.f,0.f,0.f,0.f};

    #pragma unroll
    for (int t=0;t<18;t++){
        const int j = t>>1, ih = t&1;
        const int dy = j/3-1, dx = j%3-1;
        s8v af[8];
        #pragma unroll
        for (int rf=0;rf<8;rf++){
            int row = (rf<4 ? ocg*64 + rf*16 : 256 + ocg*64 + (rf-4)*16) + col;
            af[rf] = *(const s8v*)(w2 + (size_t)row*576 + t*32 + kg*8);
        }
        s8v bfr[2];
        #pragma unroll
        for (int pf=0;pf<2;pf++){
            int tyc = w*2+pf;
            int sp = (tyc+dy+1)*18 + (col+dx+1);
            int chunk = ((sp<<3) | (ih*4+kg)) ^ (sp&7);
            bfr[pf] = *(const s8v*)(elds + (chunk<<3));
        }
        #pragma unroll
        for (int rf=0;rf<8;rf++)
            #pragma unroll
            for (int pf=0;pf<2;pf++)
                acc[rf][pf] = __builtin_amdgcn_mfma_f32_16x16x32_bf16(af[rf], bfr[pf], acc[rf][pf], 0,0,0);
    }

    #pragma unroll
    for (int rf=0;rf<4;rf++){
        #pragma unroll
        for (int pf=0;pf<2;pf++){
            int tyc = w*2+pf;
            int py = h0+tyc, px = w0+col;
            #pragma unroll
            for (int r=0;r<4;r++){
                int oc = ocg*64 + rf*16 + kg*4 + r;
                float4 bn = *(const float4*)(bnp + oc*4);
                float ve = sigmoidf_(acc[rf  ][pf][r]*bn.x + bn.y);
                float vf = sigmoidf_(acc[rf+4][pf][r]*bn.z + bn.w);
                size_t oi = (((size_t)((b<<8)+oc))<<12) + (py<<6) + px;
                out[oi] = ve*x[oi] + vf*y[oi];
            }
        }
    }
}

extern "C" void kernel_launch(void* const* d_in, const int* in_sizes, int n_in,
                              void* d_out, int out_size, void* d_ws, size_t ws_size,
                              hipStream_t stream) {
    const float* x     = (const float*)d_in[0];
    const float* y     = (const float*)d_in[1];
    const float* se_w1 = (const float*)d_in[2];
    const float* se_w2 = (const float*)d_in[3];
    const float* off_w = (const float*)d_in[4];
    const float* off_b = (const float*)d_in[5];
    const float* enc_w = (const float*)d_in[6];
    const float* enc_b = (const float*)d_in[7];
    const float* we_w  = (const float*)d_in[8];
    const float* we_b  = (const float*)d_in[9];
    const float* we_g  = (const float*)d_in[10];
    const float* we_bt = (const float*)d_in[11];
    const float* we_m  = (const float*)d_in[12];
    const float* we_v  = (const float*)d_in[13];
    const float* wf_w  = (const float*)d_in[14];
    const float* wf_b  = (const float*)d_in[15];
    const float* wf_g  = (const float*)d_in[16];
    const float* wf_bt = (const float*)d_in[17];
    const float* wf_m  = (const float*)d_in[18];
    const float* wf_v  = (const float*)d_in[19];
    float* out = (float*)d_out;

    float* ws     = (float*)d_ws;
    float* base   = ws;                       // 4194304 f
    float* off    = base + 4194304;           // 442368 f
    float* encT_f = off  + 442368;            // 524288 f (1048576 ush)
    float* sums   = encT_f + 524288;          // 1024 f
    float* scale  = sums + 1024;              // 1024 f
    float* wdcn_f = scale + 1024;             // 73728 f (147456 ush)
    float* w2f    = wdcn_f + 73728;           // 147456 f (294912 ush)
    float* bnp    = w2f  + 147456;            // 1024 f
    float* cw_f   = bnp  + 1024;              // 589824 f (147456 float4)
    float* ci_f   = cw_f + 589824;            // 589824 f (147456 int4)
    unsigned short* enc_t = (unsigned short*)encT_f;
    unsigned short* wdcn  = (unsigned short*)wdcn_f;
    unsigned short* w2    = (unsigned short*)w2f;
    float4* cwg = (float4*)cw_f;
    int4*   cig = (int4*)ci_f;
    float* part   = out;                      // d_out scratch (offconv partials): 3538944 f
    float* part2  = out;                      // d_out scratch (dcn partials): 4194304 f — disjoint lifetime

    k_wdcn        <<<576,  256, 0, stream>>>(enc_w, wdcn);
    k_wprep       <<<1152, 256, 0, stream>>>(we_w, wf_w, w2);
    k_bnprep      <<<1,    256, 0, stream>>>(we_b, we_g, we_bt, we_m, we_v,
                                             wf_b, wf_g, wf_bt, wf_m, wf_v, bnp);
    k_base_sum    <<<1024, 256, 0, stream>>>(x, y, base, sums);
    k_se          <<<4,    256, 0, stream>>>(sums, se_w1, se_w2, scale);
    k_scale       <<<16384,256, 0, stream>>>(base, scale);
    k_offconv_part<<<512,  256, 0, stream>>>(base, off_w, part);
    k_offreduce   <<<1728, 256, 0, stream>>>(part, off_b, off);
    k_prep_off    <<<576,  256, 0, stream>>>(off, cwg, cig);
    k_dcn_mfma    <<<1024, 512, 0, stream>>>(base, cwg, cig, wdcn, part2);
    k_encreduce   <<<2048, 256, 0, stream>>>(part2, enc_b, enc_t);
    k_fuse_mfma   <<<256,  512, 0, stream>>>(enc_t, w2, bnp, x, y, out);
}

// Round 9
// 339.581 us; speedup vs baseline: 5.5852x; 1.2960x over previous
//
#include <hip/hip_runtime.h>
#include <math.h>

#define BB 4
#define CH 256
#define CCH 64
#define HH 64
#define WW 64
#define HWN 4096

typedef short s8v __attribute__((ext_vector_type(8)));
typedef float f4v __attribute__((ext_vector_type(4)));

__device__ __forceinline__ float sigmoidf_(float v){ return 1.0f/(1.0f+__expf(-v)); }
__device__ __forceinline__ unsigned short f2bf(float f){
    union{float f; unsigned u;} v; v.f=f;
    unsigned r = v.u + 0x7FFF + ((v.u>>16)&1);
    return (unsigned short)(r>>16);
}

// ---------------- K0a: enc_w -> bf16 (layout already [oc][ck=c*9+k]) ----------------
__global__ __launch_bounds__(256) void k_wdcn(const float* __restrict__ w, unsigned short* __restrict__ wd){
    int i = blockIdx.x*256 + threadIdx.x;
    if (i < 147456) wd[i] = f2bf(w[i]);
}

// ---------------- K0b: gate weights -> bf16, K reordered tap-major: w2[row][j*64+ic] ----------------
__global__ __launch_bounds__(256) void k_wprep(const float* __restrict__ wew, const float* __restrict__ wfw,
                                               unsigned short* __restrict__ w2){
    int i = blockIdx.x*256+threadIdx.x;   // < 512*576
    if (i>=294912) return;
    int row = i/576, k = i-row*576;
    int j = k>>6, ic = k&63;
    float v = (row<256) ? wew[((row<<6)+ic)*9 + j] : wfw[(((row-256)<<6)+ic)*9 + j];
    w2[i] = f2bf(v);
}

// ---------------- K0d: offset-conv weights -> bf16 [32 rows][2304], k = j*256 + c ----------------
__global__ __launch_bounds__(256) void k_woff(const float* __restrict__ ow, unsigned short* __restrict__ wofft){
    int i = blockIdx.x*256+threadIdx.x;   // < 32*2304
    if (i>=73728) return;
    int ko = i/2304, k = i-ko*2304;
    int j = k>>8, c = k&255;
    float v = (ko<27) ? ow[(size_t)(ko*256+c)*9 + j] : 0.f;
    wofft[i] = f2bf(v);
}

// ---------------- K0c: fold conv-bias + BN into (inv, shift) per oc ----------------
__global__ __launch_bounds__(256) void k_bnprep(const float* __restrict__ web,const float* __restrict__ weg,
    const float* __restrict__ webt,const float* __restrict__ wem,const float* __restrict__ wev,
    const float* __restrict__ wfb,const float* __restrict__ wfg,const float* __restrict__ wfbt,
    const float* __restrict__ wfm,const float* __restrict__ wfv, float* __restrict__ bnp){
    int oc = threadIdx.x;
    float ie = weg[oc]*rsqrtf(wev[oc]+1e-5f);
    float se = webt[oc] - wem[oc]*ie + web[oc]*ie;
    float iff= wfg[oc]*rsqrtf(wfv[oc]+1e-5f);
    float sf = wfbt[oc] - wfm[oc]*iff + wfb[oc]*iff;
    *(float4*)(bnp + oc*4) = make_float4(ie, se, iff, sf);
}

// ---------------- K1: base = x+y, per-(b,c) sum ----------------
__global__ __launch_bounds__(256) void k_base_sum(const float* __restrict__ x, const float* __restrict__ y,
                                                  float* __restrict__ base, float* __restrict__ sums){
    int bc = blockIdx.x, tid = threadIdx.x;
    const float* xp = x + (size_t)bc*HWN;
    const float* yp = y + (size_t)bc*HWN;
    float* bp = base + (size_t)bc*HWN;
    float s = 0.f;
    for (int i=tid;i<HWN;i+=256){ float v = xp[i]+yp[i]; bp[i]=v; s+=v; }
    __shared__ float red[256];
    red[tid]=s; __syncthreads();
    for (int off=128; off>0; off>>=1){ if (tid<off) red[tid]+=red[tid+off]; __syncthreads(); }
    if (tid==0) sums[bc]=red[0];
}

// ---------------- K2: SE MLP -> scale = 1 + sigmoid(relu(mean@w1T)@w2T) ----------------
__global__ __launch_bounds__(256) void k_se(const float* __restrict__ sums, const float* __restrict__ w1,
                                            const float* __restrict__ w2, float* __restrict__ scale){
    int b = blockIdx.x, tid = threadIdx.x;
    __shared__ float sm[256];
    __shared__ float hid[16];
    sm[tid] = sums[b*256+tid]*(1.0f/4096.0f);
    __syncthreads();
    if (tid<16){
        float a=0.f; const float* wp = w1 + tid*256;
        for (int c=0;c<256;c++) a += sm[c]*wp[c];
        hid[tid]=fmaxf(a,0.f);
    }
    __syncthreads();
    float a=0.f; const float* wp = w2 + tid*16;
    #pragma unroll
    for (int j=0;j<16;j++) a += hid[j]*wp[j];
    scale[b*256+tid] = 1.f + sigmoidf_(a);
}

// ---------------- K3: base *= scale; also emit base_t bf16 [b][pos][c] ----------------
// grid: b(4) x cb(4) x pb(64) = 1024 blocks
__global__ __launch_bounds__(256) void k_scale_t(float* __restrict__ base, const float* __restrict__ scale,
                                                 unsigned short* __restrict__ base_t){
    int bid = blockIdx.x;
    int pb = bid&63, cb = (bid>>6)&3, b = bid>>8;
    int tid = threadIdx.x;
    __shared__ unsigned short lt[64*66];
    #pragma unroll
    for (int it=0; it<16; ++it){
        int idx = it*256 + tid;
        int c = idx>>6, p = idx&63;
        size_t gi = ((size_t)(b*256 + cb*64 + c))*4096 + pb*64 + p;
        float v = base[gi] * scale[b*256 + cb*64 + c];
        base[gi] = v;
        lt[p*66 + c] = f2bf(v);
    }
    __syncthreads();
    #pragma unroll
    for (int it=0; it<8; ++it){
        int idx = it*256 + tid;   // 0..2047: 64 pos x 32 ch-pairs
        int p = idx>>5, cp = idx&31;
        unsigned lo = lt[p*66 + cp*2], hi = lt[p*66 + cp*2+1];
        *(unsigned*)(base_t + ((size_t)(b*4096 + pb*64 + p))*256 + cb*64 + cp*2) = lo | (hi<<16);
    }
}

// ---------------- K4: offset conv via MFMA: C[32][64 pos], K=2304 tap-major ----------------
// grid: b(4) x tile(64: 8x8 of 8x8-pos) = 256 blocks, 512 thr (8 waves: rf(2) x pf(4))
__global__ __launch_bounds__(512) void k_offconv_mfma(const unsigned short* __restrict__ base_t,
    const unsigned short* __restrict__ wofft, const float* __restrict__ ob, float* __restrict__ off){
    int bid = blockIdx.x;
    int tIdx = bid&63, b = bid>>6;
    int th = tIdx>>3, tw = tIdx&7;
    int tid = threadIdx.x;
    __shared__ unsigned short plds[3200*8];   // 100 spots x 256 ch bf16, 16B-chunk XOR swizzle
    const unsigned short* bt = base_t + (((size_t)b)<<12)*256;
    for (int i=tid; i<3200; i+=512){
        int spot = i>>5, cid = i&31;
        int sy = spot/10, sx = spot - sy*10;
        int gy = th*8 + sy - 1, gx = tw*8 + sx - 1;
        uint4 v = make_uint4(0u,0u,0u,0u);
        if (gy>=0 && gy<HH && gx>=0 && gx<WW)
            v = *(const uint4*)(bt + ((size_t)((gy<<6)+gx))*256 + cid*8);
        int chunk = (spot<<5) | (cid ^ (spot&7));
        *(uint4*)(plds + (chunk<<3)) = v;
    }
    __syncthreads();
    int lane = tid&63, w = tid>>6;
    int rf = w&1, pf = w>>1;
    int col = lane&15, kg = lane>>4;
    int p = pf*16 + col, ly = p>>3, lx = p&7;
    f4v acc = (f4v){0.f,0.f,0.f,0.f};
    #pragma unroll
    for (int j=0;j<9;j++){
        int dy = j/3, dx = j%3;
        int spot = (ly+dy)*10 + lx+dx;
        const unsigned short* arow = wofft + (size_t)(rf*16+col)*2304 + j*256 + kg*8;
        #pragma unroll
        for (int s=0;s<8;s++){
            s8v a = *(const s8v*)(arow + s*32);
            int cid = s*4 + kg;
            s8v bf = *(const s8v*)(plds + (((spot<<5)|(cid^(spot&7)))<<3));
            acc = __builtin_amdgcn_mfma_f32_16x16x32_bf16(a, bf, acc, 0,0,0);
        }
    }
    int gy = th*8+ly, gx = tw*8+lx;
    #pragma unroll
    for (int r=0;r<4;r++){
        int ko = rf*16 + kg*4 + r;
        if (ko < 27)
            off[(((size_t)(b*27+ko))<<12) + (gy<<6) + gx] = acc[r] + ob[ko];
    }
}

// ---------------- K5a: per-(b,k,pos) corner weights/indices ----------------
__global__ __launch_bounds__(256) void k_prep_off(const float* __restrict__ off,
                                                  float4* __restrict__ cwg, int4* __restrict__ cig){
    int i = blockIdx.x*256+threadIdx.x;   // < 4*9*4096
    if (i >= 147456) return;
    int b = i/36864, rem = i - b*36864;
    int k = rem>>12, pos = rem&4095;
    int h = pos>>6, p = pos&63;
    const float* op = off + ((size_t)b*27<<12) + pos;
    float dy = op[(size_t)(2*k)<<12];
    float dx = op[(size_t)(2*k+1)<<12];
    float m  = sigmoidf_(op[(size_t)(18+k)<<12]);
    float py = (float)(h + k/3 - 1) + dy;
    float px = (float)(p + (k%3) - 1) + dx;
    float y0 = floorf(py), x0 = floorf(px);
    float fy1 = py - y0, fy0 = 1.f - fy1;
    float fx1 = px - x0, fx0 = 1.f - fx1;
    int iy0 = (int)y0, ix0 = (int)x0;
    bool vy0 = (y0>=0.f)&&(y0<64.f), vy1 = (y0>=-1.f)&&(y0<63.f);
    bool vx0 = (x0>=0.f)&&(x0<64.f), vx1 = (x0>=-1.f)&&(x0<63.f);
    int cy0 = min(max(iy0,0),63), cy1 = min(max(iy0+1,0),63);
    int cx0 = min(max(ix0,0),63), cx1 = min(max(ix0+1,0),63);
    float4 wv; int4 iv;
    wv.x = (vy0&&vx0)? fy0*fx0*m : 0.f;
    wv.y = (vy0&&vx1)? fy0*fx1*m : 0.f;
    wv.z = (vy1&&vx0)? fy1*fx0*m : 0.f;
    wv.w = (vy1&&vx1)? fy1*fx1*m : 0.f;
    iv.x = cy0*WW+cx0; iv.y = cy0*WW+cx1; iv.z = cy1*WW+cx0; iv.w = cy1*WW+cx1;
    cwg[i] = wv; cig[i] = iv;
}

// ---------------- K5b: DCNv2 sample (bf16) + MFMA einsum, split-K x4 ----------------
__global__ __launch_bounds__(512,4) void k_dcn_mfma(const float* __restrict__ base,
    const float4* __restrict__ cwg, const int4* __restrict__ cig,
    const unsigned short* __restrict__ wdcn, float* __restrict__ part2){
    int bid = blockIdx.x;
    int cg = bid&3, h = (bid>>2)&63, b = bid>>8;
    int tid = threadIdx.x;
    __shared__ float4 cw4[576];
    __shared__ int4   ci4[576];
    __shared__ unsigned short smp[64*64];

    for (int i=tid;i<576;i+=512){
        cw4[i] = cwg[(((size_t)b*9 + (i>>6))<<12) + (h<<6) + (i&63)];
        ci4[i] = cig[(((size_t)b*9 + (i>>6))<<12) + (h<<6) + (i&63)];
    }
    __syncthreads();

    int pos = tid&63, sgrp = tid>>6;
    int w = tid>>6, lane = tid&63;
    int mf = w&3, nh = w>>2;
    int col = lane&15, kg = lane>>4;
    f4v acc0 = (f4v){0.f,0.f,0.f,0.f}, acc1 = acc0;
    const float* bb = base + ((size_t)b*CH + cg*64)*HWN;

    for (int t=0;t<9;t++){
        unsigned int pk[4];
        #pragma unroll
        for (int i=0;i<8;i++){
            int ckL = t*64 + sgrp*8 + i;
            int c = ckL/9, k = ckL - 9*c;
            float4 wv = cw4[k*64+pos];
            int4  iv = ci4[k*64+pos];
            const float* bp = bb + (size_t)c*HWN;
            float v = wv.x*bp[iv.x] + wv.y*bp[iv.y] + wv.z*bp[iv.z] + wv.w*bp[iv.w];
            unsigned short us = f2bf(v);
            if (i&1) pk[i>>1] |= ((unsigned)us)<<16; else pk[i>>1] = (unsigned)us;
        }
        __syncthreads();
        {
            int chunk = (pos<<3) | (sgrp ^ (pos&7));
            *(uint4*)(smp + (chunk<<3)) = *(const uint4*)pk;
        }
        __syncthreads();
        #pragma unroll
        for (int ks=0;ks<2;ks++){
            int koff = cg*576 + t*64 + ks*32 + kg*8;
            s8v a = *(const s8v*)(wdcn + (size_t)(mf*16+col)*2304 + koff);
            int cgrp = ks*4+kg;
            int p0 = (nh*2)*16 + col;
            int p1 = (nh*2+1)*16 + col;
            s8v b0 = *(const s8v*)(smp + (((p0<<3)|(cgrp^(p0&7)))<<3));
            s8v b1 = *(const s8v*)(smp + (((p1<<3)|(cgrp^(p1&7)))<<3));
            acc0 = __builtin_amdgcn_mfma_f32_16x16x32_bf16(a, b0, acc0, 0,0,0);
            acc1 = __builtin_amdgcn_mfma_f32_16x16x32_bf16(a, b1, acc1, 0,0,0);
        }
    }
    float* pout = part2 + ((size_t)(cg*BB + b))*(HWN*64);
    #pragma unroll
    for (int j=0;j<2;j++){
        f4v a = j ? acc1 : acc0;
        int posg = (h<<6) + (nh*2+j)*16 + col;
        int oc = mf*16 + kg*4;
        *(float4*)(pout + (size_t)posg*64 + oc) = *(float4*)&a;
    }
}

// ---------------- K5c: sum 4 partials + bias + relu -> enc_t bf16 [b][pos][oc] ----------------
__global__ __launch_bounds__(256) void k_encreduce(const float* __restrict__ part2, const float* __restrict__ encb,
                                                   unsigned short* __restrict__ enc_t){
    int i = blockIdx.x*256+threadIdx.x;   // < 4*4096*32
    int b = i>>17, rem = i&131071;
    int pos = rem>>5, oc2 = rem&31;
    size_t basei = (((size_t)b<<12) + pos)*64 + oc2*2;
    float s0 = encb[oc2*2], s1 = encb[oc2*2+1];
    #pragma unroll
    for (int cg=0;cg<4;cg++){
        const float* p = part2 + (size_t)cg*1048576 + basei;
        s0 += p[0]; s1 += p[1];
    }
    unsigned short lo = f2bf(fmaxf(s0,0.f));
    unsigned short hi = f2bf(fmaxf(s1,0.f));
    *(unsigned int*)(enc_t + basei) = (unsigned int)lo | ((unsigned int)hi<<16);
}

// ---------------- K6: fused gate convs via MFMA bf16 + BN + sigmoid + blend ----------------
__global__ __launch_bounds__(512) void k_fuse_mfma(const unsigned short* __restrict__ enc_t,
    const unsigned short* __restrict__ w2, const float* __restrict__ bnp,
    const float* __restrict__ x, const float* __restrict__ y, float* __restrict__ out){
    int bid = blockIdx.x;
    int ocg = bid&3, tile = (bid>>2)&15, b = bid>>6;
    int h0 = (tile>>2)<<4, w0 = (tile&3)<<4;
    int tid = threadIdx.x;
    __shared__ unsigned short elds[324*64];

    const unsigned short* ebase = enc_t + (((size_t)b)<<12)*64;
    #pragma unroll
    for (int kk=0;kk<6;kk++){
        int i = tid + kk*512;
        if (i < 2592){
            int sp = i>>3, icg = i&7;
            int sy = sp/18, sx = sp - sy*18;
            int py = h0+sy-1, px = w0+sx-1;
            uint4 v = make_uint4(0u,0u,0u,0u);
            if (py>=0 && py<HH && px>=0 && px<WW)
                v = *(const uint4*)(ebase + (size_t)((py<<6)+px)*64 + (icg<<3));
            int chunk = ((sp<<3) | icg) ^ (sp&7);
            *(uint4*)(elds + (chunk<<3)) = v;
        }
    }
    __syncthreads();

    int lane = tid&63, w = tid>>6;
    int col = lane&15, kg = lane>>4;
    f4v acc[8][2];
    #pragma unroll
    for (int rf=0;rf<8;rf++)
        #pragma unroll
        for (int pf=0;pf<2;pf++) acc[rf][pf] = (f4v){0.f,0.f,0.f,0.f};

    #pragma unroll
    for (int t=0;t<18;t++){
        const int j = t>>1, ih = t&1;
        const int dy = j/3-1, dx = j%3-1;
        s8v af[8];
        #pragma unroll
        for (int rf=0;rf<8;rf++){
            int row = (rf<4 ? ocg*64 + rf*16 : 256 + ocg*64 + (rf-4)*16) + col;
            af[rf] = *(const s8v*)(w2 + (size_t)row*576 + t*32 + kg*8);
        }
        s8v bfr[2];
        #pragma unroll
        for (int pf=0;pf<2;pf++){
            int tyc = w*2+pf;
            int sp = (tyc+dy+1)*18 + (col+dx+1);
            int chunk = ((sp<<3) | (ih*4+kg)) ^ (sp&7);
            bfr[pf] = *(const s8v*)(elds + (chunk<<3));
        }
        #pragma unroll
        for (int rf=0;rf<8;rf++)
            #pragma unroll
            for (int pf=0;pf<2;pf++)
                acc[rf][pf] = __builtin_amdgcn_mfma_f32_16x16x32_bf16(af[rf], bfr[pf], acc[rf][pf], 0,0,0);
    }

    #pragma unroll
    for (int rf=0;rf<4;rf++){
        #pragma unroll
        for (int pf=0;pf<2;pf++){
            int tyc = w*2+pf;
            int py = h0+tyc, px = w0+col;
            #pragma unroll
            for (int r=0;r<4;r++){
                int oc = ocg*64 + rf*16 + kg*4 + r;
                float4 bn = *(const float4*)(bnp + oc*4);
                float ve = sigmoidf_(acc[rf  ][pf][r]*bn.x + bn.y);
                float vf = sigmoidf_(acc[rf+4][pf][r]*bn.z + bn.w);
                size_t oi = (((size_t)((b<<8)+oc))<<12) + (py<<6) + px;
                out[oi] = ve*x[oi] + vf*y[oi];
            }
        }
    }
}

extern "C" void kernel_launch(void* const* d_in, const int* in_sizes, int n_in,
                              void* d_out, int out_size, void* d_ws, size_t ws_size,
                              hipStream_t stream) {
    const float* x     = (const float*)d_in[0];
    const float* y     = (const float*)d_in[1];
    const float* se_w1 = (const float*)d_in[2];
    const float* se_w2 = (const float*)d_in[3];
    const float* off_w = (const float*)d_in[4];
    const float* off_b = (const float*)d_in[5];
    const float* enc_w = (const float*)d_in[6];
    const float* enc_b = (const float*)d_in[7];
    const float* we_w  = (const float*)d_in[8];
    const float* we_b  = (const float*)d_in[9];
    const float* we_g  = (const float*)d_in[10];
    const float* we_bt = (const float*)d_in[11];
    const float* we_m  = (const float*)d_in[12];
    const float* we_v  = (const float*)d_in[13];
    const float* wf_w  = (const float*)d_in[14];
    const float* wf_b  = (const float*)d_in[15];
    const float* wf_g  = (const float*)d_in[16];
    const float* wf_bt = (const float*)d_in[17];
    const float* wf_m  = (const float*)d_in[18];
    const float* wf_v  = (const float*)d_in[19];
    float* out = (float*)d_out;

    float* ws     = (float*)d_ws;
    float* base   = ws;                       // 4194304 f
    float* off    = base + 4194304;           // 442368 f
    float* encT_f = off  + 442368;            // 524288 f (1048576 ush)
    float* sums   = encT_f + 524288;          // 1024 f
    float* scale  = sums + 1024;              // 1024 f
    float* wdcn_f = scale + 1024;             // 73728 f (147456 ush)
    float* w2f    = wdcn_f + 73728;           // 147456 f (294912 ush)
    float* bnp    = w2f  + 147456;            // 1024 f
    float* wofft_f= bnp  + 1024;              // 36864 f (73728 ush)
    float* cw_f   = wofft_f + 36864;          // 589824 f (147456 float4)
    float* ci_f   = cw_f + 589824;            // 589824 f (147456 int4)
    unsigned short* enc_t = (unsigned short*)encT_f;
    unsigned short* wdcn  = (unsigned short*)wdcn_f;
    unsigned short* w2    = (unsigned short*)w2f;
    unsigned short* wofft = (unsigned short*)wofft_f;
    float4* cwg = (float4*)cw_f;
    int4*   cig = (int4*)ci_f;
    // d_out scratch, disjoint lifetimes:
    unsigned short* base_t = (unsigned short*)out;  // written k_scale_t, dead after k_offconv_mfma
    float* part2  = out;                            // written k_dcn_mfma, dead after k_encreduce

    k_wdcn        <<<576,  256, 0, stream>>>(enc_w, wdcn);
    k_wprep       <<<1152, 256, 0, stream>>>(we_w, wf_w, w2);
    k_woff        <<<288,  256, 0, stream>>>(off_w, wofft);
    k_bnprep      <<<1,    256, 0, stream>>>(we_b, we_g, we_bt, we_m, we_v,
                                             wf_b, wf_g, wf_bt, wf_m, wf_v, bnp);
    k_base_sum    <<<1024, 256, 0, stream>>>(x, y, base, sums);
    k_se          <<<4,    256, 0, stream>>>(sums, se_w1, se_w2, scale);
    k_scale_t     <<<1024, 256, 0, stream>>>(base, scale, base_t);
    k_offconv_mfma<<<256,  512, 0, stream>>>(base_t, wofft, off_b, off);
    k_prep_off    <<<576,  256, 0, stream>>>(off, cwg, cig);
    k_dcn_mfma    <<<1024, 512, 0, stream>>>(base, cwg, cig, wdcn, part2);
    k_encreduce   <<<2048, 256, 0, stream>>>(part2, enc_b, enc_t);
    k_fuse_mfma   <<<256,  512, 0, stream>>>(enc_t, w2, bnp, x, y, out);
}

// Round 10
// 335.416 us; speedup vs baseline: 5.6545x; 1.0124x over previous
//
#include <hip/hip_runtime.h>
#include <math.h>

#define BB 4
#define CH 256
#define CCH 64
#define HH 64
#define WW 64
#define HWN 4096

typedef short s8v __attribute__((ext_vector_type(8)));
typedef float f4v __attribute__((ext_vector_type(4)));

__device__ __forceinline__ float sigmoidf_(float v){ return 1.0f/(1.0f+__expf(-v)); }
__device__ __forceinline__ unsigned short f2bf(float f){
    union{float f; unsigned u;} v; v.f=f;
    unsigned r = v.u + 0x7FFF + ((v.u>>16)&1);
    return (unsigned short)(r>>16);
}
__device__ __forceinline__ float bf2f(unsigned short u){
    union{unsigned u; float f;} v; v.u = ((unsigned)u)<<16; return v.f;
}

// ---------------- K0: ALL weight prep fused (wdcn | w2 | wofft | bnp) ----------------
__global__ __launch_bounds__(256) void k_prepall(const float* __restrict__ enc_w,
    const float* __restrict__ wew, const float* __restrict__ wfw, const float* __restrict__ ow,
    const float* __restrict__ web, const float* __restrict__ weg, const float* __restrict__ webt,
    const float* __restrict__ wem, const float* __restrict__ wev,
    const float* __restrict__ wfb, const float* __restrict__ wfg, const float* __restrict__ wfbt,
    const float* __restrict__ wfm, const float* __restrict__ wfv,
    unsigned short* __restrict__ wdcn, unsigned short* __restrict__ w2,
    unsigned short* __restrict__ wofft, float* __restrict__ bnp){
    int i = blockIdx.x*256+threadIdx.x;
    if (i < 147456){ wdcn[i] = f2bf(enc_w[i]); return; }
    int j = i - 147456;
    if (j < 294912){
        int row = j/576, k = j-row*576;
        int t = k>>6, ic = k&63;
        float v = (row<256)? wew[((row<<6)+ic)*9+t] : wfw[(((row-256)<<6)+ic)*9+t];
        w2[j] = f2bf(v);
        return;
    }
    int m = j - 294912;
    if (m < 73728){
        int ko = m/2304, k = m-ko*2304;
        int t = k>>8, c = k&255;
        wofft[m] = f2bf((ko<27)? ow[(size_t)(ko*256+c)*9+t] : 0.f);
        return;
    }
    int n = m - 73728;
    if (n < 256){
        float ie = weg[n]*rsqrtf(wev[n]+1e-5f);
        float se = webt[n]-wem[n]*ie+web[n]*ie;
        float iff = wfg[n]*rsqrtf(wfv[n]+1e-5f);
        float sf = wfbt[n]-wfm[n]*iff+wfb[n]*iff;
        *(float4*)(bnp+n*4) = make_float4(ie,se,iff,sf);
    }
}

// ---------------- K1: base = x+y, per-(b,c) sum ----------------
__global__ __launch_bounds__(256) void k_base_sum(const float* __restrict__ x, const float* __restrict__ y,
                                                  float* __restrict__ base, float* __restrict__ sums){
    int bc = blockIdx.x, tid = threadIdx.x;
    const float* xp = x + (size_t)bc*HWN;
    const float* yp = y + (size_t)bc*HWN;
    float* bp = base + (size_t)bc*HWN;
    float s = 0.f;
    for (int i=tid;i<HWN;i+=256){ float v = xp[i]+yp[i]; bp[i]=v; s+=v; }
    __shared__ float red[256];
    red[tid]=s; __syncthreads();
    for (int off=128; off>0; off>>=1){ if (tid<off) red[tid]+=red[tid+off]; __syncthreads(); }
    if (tid==0) sums[bc]=red[0];
}

// ---------------- K2: SE MLP -> scale = 1 + sigmoid(relu(mean@w1T)@w2T) ----------------
__global__ __launch_bounds__(256) void k_se(const float* __restrict__ sums, const float* __restrict__ w1,
                                            const float* __restrict__ w2, float* __restrict__ scale){
    int b = blockIdx.x, tid = threadIdx.x;
    __shared__ float sm[256];
    __shared__ float hid[16];
    sm[tid] = sums[b*256+tid]*(1.0f/4096.0f);
    __syncthreads();
    if (tid<16){
        float a=0.f; const float* wp = w1 + tid*256;
        for (int c=0;c<256;c++) a += sm[c]*wp[c];
        hid[tid]=fmaxf(a,0.f);
    }
    __syncthreads();
    float a=0.f; const float* wp = w2 + tid*16;
    #pragma unroll
    for (int j=0;j<16;j++) a += hid[j]*wp[j];
    scale[b*256+tid] = 1.f + sigmoidf_(a);
}

// ---------------- K3: base *= scale; also emit base_t bf16 [b][pos][c] ----------------
__global__ __launch_bounds__(256) void k_scale_t(float* __restrict__ base, const float* __restrict__ scale,
                                                 unsigned short* __restrict__ base_t){
    int bid = blockIdx.x;
    int pb = bid&63, cb = (bid>>6)&3, b = bid>>8;
    int tid = threadIdx.x;
    __shared__ unsigned short lt[64*66];
    #pragma unroll
    for (int it=0; it<16; ++it){
        int idx = it*256 + tid;
        int c = idx>>6, p = idx&63;
        size_t gi = ((size_t)(b*256 + cb*64 + c))*4096 + pb*64 + p;
        float v = base[gi] * scale[b*256 + cb*64 + c];
        base[gi] = v;
        lt[p*66 + c] = f2bf(v);
    }
    __syncthreads();
    #pragma unroll
    for (int it=0; it<8; ++it){
        int idx = it*256 + tid;   // 0..2047: 64 pos x 32 ch-pairs
        int p = idx>>5, cp = idx&31;
        unsigned lo = lt[p*66 + cp*2], hi = lt[p*66 + cp*2+1];
        *(unsigned*)(base_t + ((size_t)(b*4096 + pb*64 + p))*256 + cb*64 + cp*2) = lo | (hi<<16);
    }
}

// ---------------- K4: offset conv via MFMA: C[32][64 pos], K=2304 tap-major ----------------
__global__ __launch_bounds__(512) void k_offconv_mfma(const unsigned short* __restrict__ base_t,
    const unsigned short* __restrict__ wofft, const float* __restrict__ ob, float* __restrict__ off){
    int bid = blockIdx.x;
    int tIdx = bid&63, b = bid>>6;
    int th = tIdx>>3, tw = tIdx&7;
    int tid = threadIdx.x;
    __shared__ unsigned short plds[3200*8];   // 100 spots x 256 ch bf16, 16B-chunk XOR swizzle
    const unsigned short* bt = base_t + (((size_t)b)<<12)*256;
    for (int i=tid; i<3200; i+=512){
        int spot = i>>5, cid = i&31;
        int sy = spot/10, sx = spot - sy*10;
        int gy = th*8 + sy - 1, gx = tw*8 + sx - 1;
        uint4 v = make_uint4(0u,0u,0u,0u);
        if (gy>=0 && gy<HH && gx>=0 && gx<WW)
            v = *(const uint4*)(bt + ((size_t)((gy<<6)+gx))*256 + cid*8);
        int chunk = (spot<<5) | (cid ^ (spot&7));
        *(uint4*)(plds + (chunk<<3)) = v;
    }
    __syncthreads();
    int lane = tid&63, w = tid>>6;
    int rf = w&1, pf = w>>1;
    int col = lane&15, kg = lane>>4;
    int p = pf*16 + col, ly = p>>3, lx = p&7;
    f4v acc = (f4v){0.f,0.f,0.f,0.f};
    #pragma unroll
    for (int j=0;j<9;j++){
        int dy = j/3, dx = j%3;
        int spot = (ly+dy)*10 + lx+dx;
        const unsigned short* arow = wofft + (size_t)(rf*16+col)*2304 + j*256 + kg*8;
        #pragma unroll
        for (int s=0;s<8;s++){
            s8v a = *(const s8v*)(arow + s*32);
            int cid = s*4 + kg;
            s8v bf = *(const s8v*)(plds + (((spot<<5)|(cid^(spot&7)))<<3));
            acc = __builtin_amdgcn_mfma_f32_16x16x32_bf16(a, bf, acc, 0,0,0);
        }
    }
    int gy = th*8+ly, gx = tw*8+lx;
    #pragma unroll
    for (int r=0;r<4;r++){
        int ko = rf*16 + kg*4 + r;
        if (ko < 27)
            off[(((size_t)(b*27+ko))<<12) + (gy<<6) + gx] = acc[r] + ob[ko];
    }
}

// ---------------- K5a: per-(b,k,pos) corner weights/indices ----------------
__global__ __launch_bounds__(256) void k_prep_off(const float* __restrict__ off,
                                                  float4* __restrict__ cwg, int4* __restrict__ cig){
    int i = blockIdx.x*256+threadIdx.x;   // < 4*9*4096
    if (i >= 147456) return;
    int b = i/36864, rem = i - b*36864;
    int k = rem>>12, pos = rem&4095;
    int h = pos>>6, p = pos&63;
    const float* op = off + ((size_t)b*27<<12) + pos;
    float dy = op[(size_t)(2*k)<<12];
    float dx = op[(size_t)(2*k+1)<<12];
    float m  = sigmoidf_(op[(size_t)(18+k)<<12]);
    float py = (float)(h + k/3 - 1) + dy;
    float px = (float)(p + (k%3) - 1) + dx;
    float y0 = floorf(py), x0 = floorf(px);
    float fy1 = py - y0, fy0 = 1.f - fy1;
    float fx1 = px - x0, fx0 = 1.f - fx1;
    int iy0 = (int)y0, ix0 = (int)x0;
    bool vy0 = (y0>=0.f)&&(y0<64.f), vy1 = (y0>=-1.f)&&(y0<63.f);
    bool vx0 = (x0>=0.f)&&(x0<64.f), vx1 = (x0>=-1.f)&&(x0<63.f);
    int cy0 = min(max(iy0,0),63), cy1 = min(max(iy0+1,0),63);
    int cx0 = min(max(ix0,0),63), cx1 = min(max(ix0+1,0),63);
    float4 wv; int4 iv;
    wv.x = (vy0&&vx0)? fy0*fx0*m : 0.f;
    wv.y = (vy0&&vx1)? fy0*fx1*m : 0.f;
    wv.z = (vy1&&vx0)? fy1*fx0*m : 0.f;
    wv.w = (vy1&&vx1)? fy1*fx1*m : 0.f;
    iv.x = cy0*WW+cx0; iv.y = cy0*WW+cx1; iv.z = cy1*WW+cx0; iv.w = cy1*WW+cx1;
    cwg[i] = wv; cig[i] = iv;
}

// ---------------- K5b: DCNv2 sample (bf16) + MFMA einsum, split-K x8, XCD-pinned ----------------
// grid: bid = h*32 + b*8 + cg  (2048 blocks; XCD ~ bid%8 = cg -> 2MB base slice per L2)
// block: 512 thr (8 waves), C-partial[64 oc][64 pos] over K=288 (c in [cg*32,cg*32+32))
// K chunks: 4 x 64 + 1 x 32; smp double-buffered; ONE barrier per chunk.
__global__ __launch_bounds__(512) void k_dcn_mfma(const float* __restrict__ base,
    const float4* __restrict__ cwg, const int4* __restrict__ cig,
    const unsigned short* __restrict__ wdcn, unsigned short* __restrict__ part2b){
    int bid = blockIdx.x;
    int cg = bid&7, b = (bid>>3)&3, h = bid>>5;
    int tid = threadIdx.x;
    __shared__ float4 cw4[576];
    __shared__ int4   ci4[576];
    __shared__ unsigned short smp[2][4096];   // 2 x 8KB

    for (int i=tid;i<576;i+=512){
        int k = i>>6, p = i&63;
        size_t gidx = (((size_t)b*9 + k)<<12) + (h<<6) + p;
        cw4[i] = cwg[gidx];
        ci4[i] = cig[gidx];
    }
    __syncthreads();

    int pos = tid&63, sgrp = tid>>6;
    int w = tid>>6, lane = tid&63;
    int mf = w&3, nh = w>>2;
    int col = lane&15, kg = lane>>4;
    f4v acc0 = (f4v){0.f,0.f,0.f,0.f}, acc1 = acc0;
    const float* bb = base + ((size_t)b*CH + cg*32)*HWN;
    const unsigned short* wrow = wdcn + (size_t)(mf*16+col)*2304 + cg*288;

    #pragma unroll
    for (int t=0;t<5;t++){
        if (t<4 || sgrp<4){
            unsigned int pk[4];
            #pragma unroll
            for (int i=0;i<8;i++){
                int ckL = t*64 + sgrp*8 + i;          // < 288
                int c = ckL/9, k = ckL - 9*c;         // c in [0,32)
                float4 wv = cw4[(k<<6)+pos];
                int4  iv = ci4[(k<<6)+pos];
                const float* bp = bb + (size_t)c*HWN;
                float v = wv.x*bp[iv.x] + wv.y*bp[iv.y] + wv.z*bp[iv.z] + wv.w*bp[iv.w];
                unsigned short us = f2bf(v);
                if (i&1) pk[i>>1] |= ((unsigned)us)<<16; else pk[i>>1] = (unsigned)us;
            }
            int chunk = (pos<<3) | (sgrp ^ (pos&7));
            *(uint4*)(&smp[t&1][0] + (chunk<<3)) = *(const uint4*)pk;
        }
        __syncthreads();
        const unsigned short* sb = &smp[t&1][0];
        #pragma unroll
        for (int ks=0;ks<2;ks++){
            if (t==4 && ks==1) break;                 // half chunk at t=4
            s8v a = *(const s8v*)(wrow + t*64 + ks*32 + kg*8);
            int cgrp = ks*4+kg;
            int p0 = (nh*2)*16 + col;
            int p1 = p0 + 16;
            s8v b0 = *(const s8v*)(sb + (((p0<<3)|(cgrp^(p0&7)))<<3));
            s8v b1 = *(const s8v*)(sb + (((p1<<3)|(cgrp^(p1&7)))<<3));
            acc0 = __builtin_amdgcn_mfma_f32_16x16x32_bf16(a, b0, acc0, 0,0,0);
            acc1 = __builtin_amdgcn_mfma_f32_16x16x32_bf16(a, b1, acc1, 0,0,0);
        }
        // next iteration writes smp[(t+1)&1] (other buffer); its barrier blocks overwrite of this one.
    }

    unsigned short* pout = part2b + ((size_t)(cg*BB + b))*(HWN*64);
    #pragma unroll
    for (int j=0;j<2;j++){
        f4v a = j ? acc1 : acc0;
        int posg = (h<<6) + (nh*2+j)*16 + col;
        int oc = mf*16 + kg*4;
        unsigned lo = (unsigned)f2bf(a[0]) | ((unsigned)f2bf(a[1])<<16);
        unsigned hi = (unsigned)f2bf(a[2]) | ((unsigned)f2bf(a[3])<<16);
        *(uint2*)(pout + (size_t)posg*64 + oc) = make_uint2(lo,hi);
    }
}

// ---------------- K5c: sum 8 bf16 partials + bias + relu -> enc_t bf16 [b][pos][oc] ----------------
__global__ __launch_bounds__(256) void k_encreduce(const unsigned short* __restrict__ part2b,
                                                   const float* __restrict__ encb,
                                                   unsigned short* __restrict__ enc_t){
    int i = blockIdx.x*256+threadIdx.x;   // < 4*4096*32
    int b = i>>17, rem = i&131071;
    int pos = rem>>5, oc2 = rem&31;
    size_t basei = (((size_t)b<<12) + pos)*64 + oc2*2;
    float s0 = encb[oc2*2], s1 = encb[oc2*2+1];
    #pragma unroll
    for (int cg=0;cg<8;cg++){
        unsigned pv = *(const unsigned*)(part2b + (size_t)cg*1048576 + basei);
        s0 += bf2f((unsigned short)(pv & 0xFFFFu));
        s1 += bf2f((unsigned short)(pv >> 16));
    }
    unsigned short lo = f2bf(fmaxf(s0,0.f));
    unsigned short hi = f2bf(fmaxf(s1,0.f));
    *(unsigned int*)(enc_t + basei) = (unsigned int)lo | ((unsigned int)hi<<16);
}

// ---------------- K6: fused gate convs via MFMA bf16 + BN + sigmoid + blend ----------------
__global__ __launch_bounds__(512) void k_fuse_mfma(const unsigned short* __restrict__ enc_t,
    const unsigned short* __restrict__ w2, const float* __restrict__ bnp,
    const float* __restrict__ x, const float* __restrict__ y, float* __restrict__ out){
    int bid = blockIdx.x;
    int ocg = bid&3, tile = (bid>>2)&15, b = bid>>6;
    int h0 = (tile>>2)<<4, w0 = (tile&3)<<4;
    int tid = threadIdx.x;
    __shared__ unsigned short elds[324*64];

    const unsigned short* ebase = enc_t + (((size_t)b)<<12)*64;
    #pragma unroll
    for (int kk=0;kk<6;kk++){
        int i = tid + kk*512;
        if (i < 2592){
            int sp = i>>3, icg = i&7;
            int sy = sp/18, sx = sp - sy*18;
            int py = h0+sy-1, px = w0+sx-1;
            uint4 v = make_uint4(0u,0u,0u,0u);
            if (py>=0 && py<HH && px>=0 && px<WW)
                v = *(const uint4*)(ebase + (size_t)((py<<6)+px)*64 + (icg<<3));
            int chunk = ((sp<<3) | icg) ^ (sp&7);
            *(uint4*)(elds + (chunk<<3)) = v;
        }
    }
    __syncthreads();

    int lane = tid&63, w = tid>>6;
    int col = lane&15, kg = lane>>4;
    f4v acc[8][2];
    #pragma unroll
    for (int rf=0;rf<8;rf++)
        #pragma unroll
        for (int pf=0;pf<2;pf++) acc[rf][pf] = (f4v){0.f,0.f,0.f,0.f};

    #pragma unroll
    for (int t=0;t<18;t++){
        const int j = t>>1, ih = t&1;
        const int dy = j/3-1, dx = j%3-1;
        s8v af[8];
        #pragma unroll
        for (int rf=0;rf<8;rf++){
            int row = (rf<4 ? ocg*64 + rf*16 : 256 + ocg*64 + (rf-4)*16) + col;
            af[rf] = *(const s8v*)(w2 + (size_t)row*576 + t*32 + kg*8);
        }
        s8v bfr[2];
        #pragma unroll
        for (int pf=0;pf<2;pf++){
            int tyc = w*2+pf;
            int sp = (tyc+dy+1)*18 + (col+dx+1);
            int chunk = ((sp<<3) | (ih*4+kg)) ^ (sp&7);
            bfr[pf] = *(const s8v*)(elds + (chunk<<3));
        }
        #pragma unroll
        for (int rf=0;rf<8;rf++)
            #pragma unroll
            for (int pf=0;pf<2;pf++)
                acc[rf][pf] = __builtin_amdgcn_mfma_f32_16x16x32_bf16(af[rf], bfr[pf], acc[rf][pf], 0,0,0);
    }

    #pragma unroll
    for (int rf=0;rf<4;rf++){
        #pragma unroll
        for (int pf=0;pf<2;pf++){
            int tyc = w*2+pf;
            int py = h0+tyc, px = w0+col;
            #pragma unroll
            for (int r=0;r<4;r++){
                int oc = ocg*64 + rf*16 + kg*4 + r;
                float4 bn = *(const float4*)(bnp + oc*4);
                float ve = sigmoidf_(acc[rf  ][pf][r]*bn.x + bn.y);
                float vf = sigmoidf_(acc[rf+4][pf][r]*bn.z + bn.w);
                size_t oi = (((size_t)((b<<8)+oc))<<12) + (py<<6) + px;
                out[oi] = ve*x[oi] + vf*y[oi];
            }
        }
    }
}

extern "C" void kernel_launch(void* const* d_in, const int* in_sizes, int n_in,
                              void* d_out, int out_size, void* d_ws, size_t ws_size,
                              hipStream_t stream) {
    const float* x     = (const float*)d_in[0];
    const float* y     = (const float*)d_in[1];
    const float* se_w1 = (const float*)d_in[2];
    const float* se_w2 = (const float*)d_in[3];
    const float* off_w = (const float*)d_in[4];
    const float* off_b = (const float*)d_in[5];
    const float* enc_w = (const float*)d_in[6];
    const float* enc_b = (const float*)d_in[7];
    const float* we_w  = (const float*)d_in[8];
    const float* we_b  = (const float*)d_in[9];
    const float* we_g  = (const float*)d_in[10];
    const float* we_bt = (const float*)d_in[11];
    const float* we_m  = (const float*)d_in[12];
    const float* we_v  = (const float*)d_in[13];
    const float* wf_w  = (const float*)d_in[14];
    const float* wf_b  = (const float*)d_in[15];
    const float* wf_g  = (const float*)d_in[16];
    const float* wf_bt = (const float*)d_in[17];
    const float* wf_m  = (const float*)d_in[18];
    const float* wf_v  = (const float*)d_in[19];
    float* out = (float*)d_out;

    float* ws     = (float*)d_ws;
    float* base   = ws;                       // 4194304 f
    float* off    = base + 4194304;           // 442368 f
    float* encT_f = off  + 442368;            // 524288 f (1048576 ush)
    float* sums   = encT_f + 524288;          // 1024 f
    float* scale  = sums + 1024;              // 1024 f
    float* wdcn_f = scale + 1024;             // 73728 f (147456 ush)
    float* w2f    = wdcn_f + 73728;           // 147456 f (294912 ush)
    float* bnp    = w2f  + 147456;            // 1024 f
    float* wofft_f= bnp  + 1024;              // 36864 f (73728 ush)
    float* cw_f   = wofft_f + 36864;          // 589824 f (147456 float4)
    float* ci_f   = cw_f + 589824;            // 589824 f (147456 int4)
    unsigned short* enc_t = (unsigned short*)encT_f;
    unsigned short* wdcn  = (unsigned short*)wdcn_f;
    unsigned short* w2    = (unsigned short*)w2f;
    unsigned short* wofft = (unsigned short*)wofft_f;
    float4* cwg = (float4*)cw_f;
    int4*   cig = (int4*)ci_f;
    // d_out scratch, disjoint lifetimes:
    unsigned short* base_t = (unsigned short*)out;  // k_scale_t -> k_offconv_mfma
    unsigned short* part2b = (unsigned short*)out;  // k_dcn_mfma -> k_encreduce (8*4*4096*64 ush = 16.78MB)

    k_prepall     <<<2018, 256, 0, stream>>>(enc_w, we_w, wf_w, off_w,
                                             we_b, we_g, we_bt, we_m, we_v,
                                             wf_b, wf_g, wf_bt, wf_m, wf_v,
                                             wdcn, w2, wofft, bnp);
    k_base_sum    <<<1024, 256, 0, stream>>>(x, y, base, sums);
    k_se          <<<4,    256, 0, stream>>>(sums, se_w1, se_w2, scale);
    k_scale_t     <<<1024, 256, 0, stream>>>(base, scale, base_t);
    k_offconv_mfma<<<256,  512, 0, stream>>>(base_t, wofft, off_b, off);
    k_prep_off    <<<576,  256, 0, stream>>>(off, cwg, cig);
    k_dcn_mfma    <<<2048, 512, 0, stream>>>(base, cwg, cig, wdcn, part2b);
    k_encreduce   <<<2048, 256, 0, stream>>>(part2b, enc_b, enc_t);
    k_fuse_mfma   <<<256,  512, 0, stream>>>(enc_t, w2, bnp, x, y, out);
}

// Round 11
// 240.634 us; speedup vs baseline: 7.8818x; 1.3939x over previous
//
#include <hip/hip_runtime.h>
#include <math.h>

#define BB 4
#define CH 256
#define CCH 64
#define HH 64
#define WW 64
#define HWN 4096

typedef short s8v __attribute__((ext_vector_type(8)));
typedef float f4v __attribute__((ext_vector_type(4)));

__device__ __forceinline__ float sigmoidf_(float v){ return 1.0f/(1.0f+__expf(-v)); }
__device__ __forceinline__ unsigned short f2bf(float f){
    union{float f; unsigned u;} v; v.f=f;
    unsigned r = v.u + 0x7FFF + ((v.u>>16)&1);
    return (unsigned short)(r>>16);
}
__device__ __forceinline__ float bf2f(unsigned short u){
    union{unsigned u; float f;} v; v.u = ((unsigned)u)<<16; return v.f;
}

// ---------------- K0: ALL weight prep fused (wdcn tap-major | w2 | wofft | bnp) ----------------
__global__ __launch_bounds__(256) void k_prepall(const float* __restrict__ enc_w,
    const float* __restrict__ wew, const float* __restrict__ wfw, const float* __restrict__ ow,
    const float* __restrict__ web, const float* __restrict__ weg, const float* __restrict__ webt,
    const float* __restrict__ wem, const float* __restrict__ wev,
    const float* __restrict__ wfb, const float* __restrict__ wfg, const float* __restrict__ wfbt,
    const float* __restrict__ wfm, const float* __restrict__ wfv,
    unsigned short* __restrict__ wdcn, unsigned short* __restrict__ w2,
    unsigned short* __restrict__ wofft, float* __restrict__ bnp){
    int i = blockIdx.x*256+threadIdx.x;
    if (i < 147456){
        // wdcn[oc][k*256+c] = enc_w[oc][c*9+k]  (tap-major K)
        int oc = i/2304, kk = i-oc*2304;
        int k = kk>>8, c = kk&255;
        wdcn[i] = f2bf(enc_w[(size_t)oc*2304 + c*9 + k]);
        return;
    }
    int j = i - 147456;
    if (j < 294912){
        int row = j/576, k = j-row*576;
        int t = k>>6, ic = k&63;
        float v = (row<256)? wew[((row<<6)+ic)*9+t] : wfw[(((row-256)<<6)+ic)*9+t];
        w2[j] = f2bf(v);
        return;
    }
    int m = j - 294912;
    if (m < 73728){
        int ko = m/2304, k = m-ko*2304;
        int t = k>>8, c = k&255;
        wofft[m] = f2bf((ko<27)? ow[(size_t)(ko*256+c)*9+t] : 0.f);
        return;
    }
    int n = m - 73728;
    if (n < 256){
        float ie = weg[n]*rsqrtf(wev[n]+1e-5f);
        float se = webt[n]-wem[n]*ie+web[n]*ie;
        float iff = wfg[n]*rsqrtf(wfv[n]+1e-5f);
        float sf = wfbt[n]-wfm[n]*iff+wfb[n]*iff;
        *(float4*)(bnp+n*4) = make_float4(ie,se,iff,sf);
    }
}

// ---------------- K1: base = x+y, per-(b,c) sum ----------------
__global__ __launch_bounds__(256) void k_base_sum(const float* __restrict__ x, const float* __restrict__ y,
                                                  float* __restrict__ base, float* __restrict__ sums){
    int bc = blockIdx.x, tid = threadIdx.x;
    const float* xp = x + (size_t)bc*HWN;
    const float* yp = y + (size_t)bc*HWN;
    float* bp = base + (size_t)bc*HWN;
    float s = 0.f;
    for (int i=tid;i<HWN;i+=256){ float v = xp[i]+yp[i]; bp[i]=v; s+=v; }
    __shared__ float red[256];
    red[tid]=s; __syncthreads();
    for (int off=128; off>0; off>>=1){ if (tid<off) red[tid]+=red[tid+off]; __syncthreads(); }
    if (tid==0) sums[bc]=red[0];
}

// ---------------- K2: SE MLP -> scale = 1 + sigmoid(relu(mean@w1T)@w2T) ----------------
__global__ __launch_bounds__(256) void k_se(const float* __restrict__ sums, const float* __restrict__ w1,
                                            const float* __restrict__ w2, float* __restrict__ scale){
    int b = blockIdx.x, tid = threadIdx.x;
    __shared__ float sm[256];
    __shared__ float hid[16];
    sm[tid] = sums[b*256+tid]*(1.0f/4096.0f);
    __syncthreads();
    if (tid<16){
        float a=0.f; const float* wp = w1 + tid*256;
        for (int c=0;c<256;c++) a += sm[c]*wp[c];
        hid[tid]=fmaxf(a,0.f);
    }
    __syncthreads();
    float a=0.f; const float* wp = w2 + tid*16;
    #pragma unroll
    for (int j=0;j<16;j++) a += hid[j]*wp[j];
    scale[b*256+tid] = 1.f + sigmoidf_(a);
}

// ---------------- K3: emit base_t bf16 [b][pos][c] = base*scale (no fp32 write-back) ----------------
__global__ __launch_bounds__(256) void k_scale_t(const float* __restrict__ base, const float* __restrict__ scale,
                                                 unsigned short* __restrict__ base_t){
    int bid = blockIdx.x;
    int pb = bid&63, cb = (bid>>6)&3, b = bid>>8;
    int tid = threadIdx.x;
    __shared__ unsigned short lt[64*66];
    #pragma unroll
    for (int it=0; it<16; ++it){
        int idx = it*256 + tid;
        int c = idx>>6, p = idx&63;
        size_t gi = ((size_t)(b*256 + cb*64 + c))*4096 + pb*64 + p;
        float v = base[gi] * scale[b*256 + cb*64 + c];
        lt[p*66 + c] = f2bf(v);
    }
    __syncthreads();
    #pragma unroll
    for (int it=0; it<8; ++it){
        int idx = it*256 + tid;   // 0..2047: 64 pos x 32 ch-pairs
        int p = idx>>5, cp = idx&31;
        unsigned lo = lt[p*66 + cp*2], hi = lt[p*66 + cp*2+1];
        *(unsigned*)(base_t + ((size_t)(b*4096 + pb*64 + p))*256 + cb*64 + cp*2) = lo | (hi<<16);
    }
}

// ---------------- K4: offset conv via MFMA: C[32][64 pos], K=2304 tap-major ----------------
__global__ __launch_bounds__(512) void k_offconv_mfma(const unsigned short* __restrict__ base_t,
    const unsigned short* __restrict__ wofft, const float* __restrict__ ob, float* __restrict__ off){
    int bid = blockIdx.x;
    int tIdx = bid&63, b = bid>>6;
    int th = tIdx>>3, tw = tIdx&7;
    int tid = threadIdx.x;
    __shared__ unsigned short plds[3200*8];   // 100 spots x 256 ch bf16, 16B-chunk XOR swizzle
    const unsigned short* bt = base_t + (((size_t)b)<<12)*256;
    for (int i=tid; i<3200; i+=512){
        int spot = i>>5, cid = i&31;
        int sy = spot/10, sx = spot - sy*10;
        int gy = th*8 + sy - 1, gx = tw*8 + sx - 1;
        uint4 v = make_uint4(0u,0u,0u,0u);
        if (gy>=0 && gy<HH && gx>=0 && gx<WW)
            v = *(const uint4*)(bt + ((size_t)((gy<<6)+gx))*256 + cid*8);
        int chunk = (spot<<5) | (cid ^ (spot&7));
        *(uint4*)(plds + (chunk<<3)) = v;
    }
    __syncthreads();
    int lane = tid&63, w = tid>>6;
    int rf = w&1, pf = w>>1;
    int col = lane&15, kg = lane>>4;
    int p = pf*16 + col, ly = p>>3, lx = p&7;
    f4v acc = (f4v){0.f,0.f,0.f,0.f};
    #pragma unroll
    for (int j=0;j<9;j++){
        int dy = j/3, dx = j%3;
        int spot = (ly+dy)*10 + lx+dx;
        const unsigned short* arow = wofft + (size_t)(rf*16+col)*2304 + j*256 + kg*8;
        #pragma unroll
        for (int s=0;s<8;s++){
            s8v a = *(const s8v*)(arow + s*32);
            int cid = s*4 + kg;
            s8v bf = *(const s8v*)(plds + (((spot<<5)|(cid^(spot&7)))<<3));
            acc = __builtin_amdgcn_mfma_f32_16x16x32_bf16(a, bf, acc, 0,0,0);
        }
    }
    int gy = th*8+ly, gx = tw*8+lx;
    #pragma unroll
    for (int r=0;r<4;r++){
        int ko = rf*16 + kg*4 + r;
        if (ko < 27)
            off[(((size_t)(b*27+ko))<<12) + (gy<<6) + gx] = acc[r] + ob[ko];
    }
}

// ---------------- K5a: per-(b,k,pos) corner weights/indices ----------------
__global__ __launch_bounds__(256) void k_prep_off(const float* __restrict__ off,
                                                  float4* __restrict__ cwg, int4* __restrict__ cig){
    int i = blockIdx.x*256+threadIdx.x;   // < 4*9*4096
    if (i >= 147456) return;
    int b = i/36864, rem = i - b*36864;
    int k = rem>>12, pos = rem&4095;
    int h = pos>>6, p = pos&63;
    const float* op = off + ((size_t)b*27<<12) + pos;
    float dy = op[(size_t)(2*k)<<12];
    float dx = op[(size_t)(2*k+1)<<12];
    float m  = sigmoidf_(op[(size_t)(18+k)<<12]);
    float py = (float)(h + k/3 - 1) + dy;
    float px = (float)(p + (k%3) - 1) + dx;
    float y0 = floorf(py), x0 = floorf(px);
    float fy1 = py - y0, fy0 = 1.f - fy1;
    float fx1 = px - x0, fx0 = 1.f - fx1;
    int iy0 = (int)y0, ix0 = (int)x0;
    bool vy0 = (y0>=0.f)&&(y0<64.f), vy1 = (y0>=-1.f)&&(y0<63.f);
    bool vx0 = (x0>=0.f)&&(x0<64.f), vx1 = (x0>=-1.f)&&(x0<63.f);
    int cy0 = min(max(iy0,0),63), cy1 = min(max(iy0+1,0),63);
    int cx0 = min(max(ix0,0),63), cx1 = min(max(ix0+1,0),63);
    float4 wv; int4 iv;
    wv.x = (vy0&&vx0)? fy0*fx0*m : 0.f;
    wv.y = (vy0&&vx1)? fy0*fx1*m : 0.f;
    wv.z = (vy1&&vx0)? fy1*fx0*m : 0.f;
    wv.w = (vy1&&vx1)? fy1*fx1*m : 0.f;
    iv.x = cy0*WW+cx0; iv.y = cy0*WW+cx1; iv.z = cy1*WW+cx0; iv.w = cy1*WW+cx1;
    cwg[i] = wv; cig[i] = iv;
}

// ---------------- K5b: DCNv2 channel-contiguous sample + MFMA, split-K x4, XCD-pinned ----------------
// grid: bid = h*16 + b*4 + cg (1024 blocks; XCD ~ bid%8 -> fixed (b,cg) slices, ~1MB/XCD)
// block: 512 thr (8 waves); sampling thread = (pos, 8-ch group); K tap-major: chunk t = tap t (64 ch)
__global__ __launch_bounds__(512) void k_dcn_mfma(const unsigned short* __restrict__ base_t,
    const float4* __restrict__ cwg, const int4* __restrict__ cig,
    const unsigned short* __restrict__ wdcn, unsigned short* __restrict__ part2b){
    int bid = blockIdx.x;
    int cg = bid&3, b = (bid>>2)&3, h = bid>>4;
    int tid = threadIdx.x;
    __shared__ float4 cw4[576];
    __shared__ int4   ci4[576];
    __shared__ unsigned short smp[2][4096];   // [pos][64 ck] bf16, double-buffered, XOR swizzle

    for (int i=tid;i<576;i+=512){
        int k = i>>6, p = i&63;
        size_t g = (((size_t)b*9 + k)<<12) + (h<<6) + p;
        cw4[i] = cwg[g];
        ci4[i] = cig[g];
    }
    __syncthreads();

    int pos = tid>>3, cv = tid&7;
    int w = tid>>6, lane = tid&63;
    int mf = w&3, nh = w>>2;
    int col = lane&15, kg = lane>>4;
    f4v acc0 = (f4v){0.f,0.f,0.f,0.f}, acc1 = acc0;
    const unsigned short* bt = base_t + (((size_t)b)<<12)*256 + cg*64 + cv*8;
    const unsigned short* wrow = wdcn + (size_t)(mf*16+col)*2304 + cg*64;

    #pragma unroll
    for (int t=0;t<9;t++){
        // sample 8 contiguous channels at (tap t, pos): 4 coalesced 16B corner loads
        float4 wv = cw4[t*64+pos];
        int4  iv = ci4[t*64+pos];
        uint4 r0 = *(const uint4*)(bt + ((size_t)iv.x<<8));
        uint4 r1 = *(const uint4*)(bt + ((size_t)iv.y<<8));
        uint4 r2 = *(const uint4*)(bt + ((size_t)iv.z<<8));
        uint4 r3 = *(const uint4*)(bt + ((size_t)iv.w<<8));
        const unsigned* q0=(const unsigned*)&r0;
        const unsigned* q1=(const unsigned*)&r1;
        const unsigned* q2=(const unsigned*)&r2;
        const unsigned* q3=(const unsigned*)&r3;
        unsigned pk[4];
        #pragma unroll
        for (int d=0;d<4;d++){
            float lo = wv.x*bf2f((unsigned short)(q0[d]&0xFFFFu)) + wv.y*bf2f((unsigned short)(q1[d]&0xFFFFu))
                     + wv.z*bf2f((unsigned short)(q2[d]&0xFFFFu)) + wv.w*bf2f((unsigned short)(q3[d]&0xFFFFu));
            float hi = wv.x*bf2f((unsigned short)(q0[d]>>16)) + wv.y*bf2f((unsigned short)(q1[d]>>16))
                     + wv.z*bf2f((unsigned short)(q2[d]>>16)) + wv.w*bf2f((unsigned short)(q3[d]>>16));
            pk[d] = (unsigned)f2bf(lo) | ((unsigned)f2bf(hi)<<16);
        }
        *(uint4*)(&smp[t&1][0] + (((pos<<3)|(cv^(pos&7)))<<3)) = *(const uint4*)pk;
        __syncthreads();
        const unsigned short* sb = &smp[t&1][0];
        #pragma unroll
        for (int ks=0;ks<2;ks++){
            s8v a = *(const s8v*)(wrow + t*256 + ks*32 + kg*8);
            int cgrp = ks*4+kg;
            int p0 = (nh*2)*16 + col;
            int p1 = p0 + 16;
            s8v b0 = *(const s8v*)(sb + (((p0<<3)|(cgrp^(p0&7)))<<3));
            s8v b1 = *(const s8v*)(sb + (((p1<<3)|(cgrp^(p1&7)))<<3));
            acc0 = __builtin_amdgcn_mfma_f32_16x16x32_bf16(a, b0, acc0, 0,0,0);
            acc1 = __builtin_amdgcn_mfma_f32_16x16x32_bf16(a, b1, acc1, 0,0,0);
        }
        // next iter writes the other buffer; its barrier protects this one (reads drained pre-barrier)
    }

    unsigned short* pout = part2b + ((size_t)(cg*BB + b))*(HWN*64);
    #pragma unroll
    for (int j=0;j<2;j++){
        f4v a = j ? acc1 : acc0;
        int posg = (h<<6) + (nh*2+j)*16 + col;
        int oc = mf*16 + kg*4;
        unsigned lo = (unsigned)f2bf(a[0]) | ((unsigned)f2bf(a[1])<<16);
        unsigned hi = (unsigned)f2bf(a[2]) | ((unsigned)f2bf(a[3])<<16);
        *(uint2*)(pout + (size_t)posg*64 + oc) = make_uint2(lo,hi);
    }
}

// ---------------- K5c: sum 4 bf16 partials + bias + relu -> enc_t bf16 [b][pos][oc] ----------------
__global__ __launch_bounds__(256) void k_encreduce(const unsigned short* __restrict__ part2b,
                                                   const float* __restrict__ encb,
                                                   unsigned short* __restrict__ enc_t){
    int i = blockIdx.x*256+threadIdx.x;   // < 4*4096*32
    int b = i>>17, rem = i&131071;
    int pos = rem>>5, oc2 = rem&31;
    size_t basei = (((size_t)b<<12) + pos)*64 + oc2*2;
    float s0 = encb[oc2*2], s1 = encb[oc2*2+1];
    #pragma unroll
    for (int cg=0;cg<4;cg++){
        unsigned pv = *(const unsigned*)(part2b + (size_t)cg*1048576 + basei);
        s0 += bf2f((unsigned short)(pv & 0xFFFFu));
        s1 += bf2f((unsigned short)(pv >> 16));
    }
    unsigned short lo = f2bf(fmaxf(s0,0.f));
    unsigned short hi = f2bf(fmaxf(s1,0.f));
    *(unsigned int*)(enc_t + basei) = (unsigned int)lo | ((unsigned int)hi<<16);
}

// ---------------- K6: fused gate convs via MFMA bf16 + BN + sigmoid + blend ----------------
__global__ __launch_bounds__(512) void k_fuse_mfma(const unsigned short* __restrict__ enc_t,
    const unsigned short* __restrict__ w2, const float* __restrict__ bnp,
    const float* __restrict__ x, const float* __restrict__ y, float* __restrict__ out){
    int bid = blockIdx.x;
    int ocg = bid&3, tile = (bid>>2)&15, b = bid>>6;
    int h0 = (tile>>2)<<4, w0 = (tile&3)<<4;
    int tid = threadIdx.x;
    __shared__ unsigned short elds[324*64];

    const unsigned short* ebase = enc_t + (((size_t)b)<<12)*64;
    #pragma unroll
    for (int kk=0;kk<6;kk++){
        int i = tid + kk*512;
        if (i < 2592){
            int sp = i>>3, icg = i&7;
            int sy = sp/18, sx = sp - sy*18;
            int py = h0+sy-1, px = w0+sx-1;
            uint4 v = make_uint4(0u,0u,0u,0u);
            if (py>=0 && py<HH && px>=0 && px<WW)
                v = *(const uint4*)(ebase + (size_t)((py<<6)+px)*64 + (icg<<3));
            int chunk = ((sp<<3) | icg) ^ (sp&7);
            *(uint4*)(elds + (chunk<<3)) = v;
        }
    }
    __syncthreads();

    int lane = tid&63, w = tid>>6;
    int col = lane&15, kg = lane>>4;
    f4v acc[8][2];
    #pragma unroll
    for (int rf=0;rf<8;rf++)
        #pragma unroll
        for (int pf=0;pf<2;pf++) acc[rf][pf] = (f4v){0.f,0.f,0.f,0.f};

    #pragma unroll
    for (int t=0;t<18;t++){
        const int j = t>>1, ih = t&1;
        const int dy = j/3-1, dx = j%3-1;
        s8v af[8];
        #pragma unroll
        for (int rf=0;rf<8;rf++){
            int row = (rf<4 ? ocg*64 + rf*16 : 256 + ocg*64 + (rf-4)*16) + col;
            af[rf] = *(const s8v*)(w2 + (size_t)row*576 + t*32 + kg*8);
        }
        s8v bfr[2];
        #pragma unroll
        for (int pf=0;pf<2;pf++){
            int tyc = w*2+pf;
            int sp = (tyc+dy+1)*18 + (col+dx+1);
            int chunk = ((sp<<3) | (ih*4+kg)) ^ (sp&7);
            bfr[pf] = *(const s8v*)(elds + (chunk<<3));
        }
        #pragma unroll
        for (int rf=0;rf<8;rf++)
            #pragma unroll
            for (int pf=0;pf<2;pf++)
                acc[rf][pf] = __builtin_amdgcn_mfma_f32_16x16x32_bf16(af[rf], bfr[pf], acc[rf][pf], 0,0,0);
    }

    #pragma unroll
    for (int rf=0;rf<4;rf++){
        #pragma unroll
        for (int pf=0;pf<2;pf++){
            int tyc = w*2+pf;
            int py = h0+tyc, px = w0+col;
            #pragma unroll
            for (int r=0;r<4;r++){
                int oc = ocg*64 + rf*16 + kg*4 + r;
                float4 bn = *(const float4*)(bnp + oc*4);
                float ve = sigmoidf_(acc[rf  ][pf][r]*bn.x + bn.y);
                float vf = sigmoidf_(acc[rf+4][pf][r]*bn.z + bn.w);
                size_t oi = (((size_t)((b<<8)+oc))<<12) + (py<<6) + px;
                out[oi] = ve*x[oi] + vf*y[oi];
            }
        }
    }
}

extern "C" void kernel_launch(void* const* d_in, const int* in_sizes, int n_in,
                              void* d_out, int out_size, void* d_ws, size_t ws_size,
                              hipStream_t stream) {
    const float* x     = (const float*)d_in[0];
    const float* y     = (const float*)d_in[1];
    const float* se_w1 = (const float*)d_in[2];
    const float* se_w2 = (const float*)d_in[3];
    const float* off_w = (const float*)d_in[4];
    const float* off_b = (const float*)d_in[5];
    const float* enc_w = (const float*)d_in[6];
    const float* enc_b = (const float*)d_in[7];
    const float* we_w  = (const float*)d_in[8];
    const float* we_b  = (const float*)d_in[9];
    const float* we_g  = (const float*)d_in[10];
    const float* we_bt = (const float*)d_in[11];
    const float* we_m  = (const float*)d_in[12];
    const float* we_v  = (const float*)d_in[13];
    const float* wf_w  = (const float*)d_in[14];
    const float* wf_b  = (const float*)d_in[15];
    const float* wf_g  = (const float*)d_in[16];
    const float* wf_bt = (const float*)d_in[17];
    const float* wf_m  = (const float*)d_in[18];
    const float* wf_v  = (const float*)d_in[19];
    float* out = (float*)d_out;

    float* ws     = (float*)d_ws;
    float* base   = ws;                       // 4194304 f
    float* off    = base + 4194304;           // 442368 f
    float* encT_f = off  + 442368;            // 524288 f (1048576 ush)
    float* sums   = encT_f + 524288;          // 1024 f
    float* scale  = sums + 1024;              // 1024 f
    float* wdcn_f = scale + 1024;             // 73728 f (147456 ush)
    float* w2f    = wdcn_f + 73728;           // 147456 f (294912 ush)
    float* bnp    = w2f  + 147456;            // 1024 f
    float* wofft_f= bnp  + 1024;              // 36864 f (73728 ush)
    float* cw_f   = wofft_f + 36864;          // 589824 f (147456 float4)
    float* ci_f   = cw_f + 589824;            // 589824 f (147456 int4)
    unsigned short* enc_t = (unsigned short*)encT_f;
    unsigned short* wdcn  = (unsigned short*)wdcn_f;
    unsigned short* w2    = (unsigned short*)w2f;
    unsigned short* wofft = (unsigned short*)wofft_f;
    float4* cwg = (float4*)cw_f;
    int4*   cig = (int4*)ci_f;
    // d_out scratch, two disjoint 8.39MB halves:
    unsigned short* base_t = (unsigned short*)out;            // [0, 8.39MB): k_scale_t -> k_offconv/k_dcn
    unsigned short* part2b = (unsigned short*)out + 4194304;  // [8.39, 16.78MB): k_dcn -> k_encreduce

    k_prepall     <<<2018, 256, 0, stream>>>(enc_w, we_w, wf_w, off_w,
                                             we_b, we_g, we_bt, we_m, we_v,
                                             wf_b, wf_g, wf_bt, wf_m, wf_v,
                                             wdcn, w2, wofft, bnp);
    k_base_sum    <<<1024, 256, 0, stream>>>(x, y, base, sums);
    k_se          <<<4,    256, 0, stream>>>(sums, se_w1, se_w2, scale);
    k_scale_t     <<<1024, 256, 0, stream>>>(base, scale, base_t);
    k_offconv_mfma<<<256,  512, 0, stream>>>(base_t, wofft, off_b, off);
    k_prep_off    <<<576,  256, 0, stream>>>(off, cwg, cig);
    k_dcn_mfma    <<<1024, 512, 0, stream>>>(base_t, cwg, cig, wdcn, part2b);
    k_encreduce   <<<2048, 256, 0, stream>>>(part2b, enc_b, enc_t);
    k_fuse_mfma   <<<256,  512, 0, stream>>>(enc_t, w2, bnp, x, y, out);
}